// Round 11
// baseline (2349.884 us; speedup 1.0000x reference)
//
#include <hip/hip_runtime.h>

#define N_NODES 8192
#define N_EDGES 131072
#define NGRAPH  64
#define DIM     32
#define HID     128
#define KHALF   64         // k per half-block
#define G_NODES 4          // nodes per block
#define SROW    36         // S d-stride: 16B-aligned; +swizzle for bank spread

__device__ __forceinline__ float sigmoidf_(float x) { return 1.0f / (1.0f + expf(-x)); }

// ---------------- prep (R3-verified) ----------------
__global__ void prep1_kernel(const float* __restrict__ x, const float* __restrict__ w,
                             const float* __restrict__ b, float* __restrict__ out,
                             const int* __restrict__ dst, int* __restrict__ counts) {
  const int bb = blockIdx.x;
  if (bb < 1024) {
    int idx = bb * 256 + threadIdx.x;
    int n = idx >> 5, d = idx & 31;
    out[idx] = fmaxf(fmaf(x[n], w[d], b[d]), 0.0f);
  } else {
    int e = (bb - 1024) * 256 + threadIdx.x;
    atomicAdd(&counts[dst[e]], 1);
  }
}

__global__ void scan_kernel(const int* __restrict__ counts,
                            int* __restrict__ offsets,
                            float* __restrict__ deg_inv) {
  __shared__ int sm[1024];
  int t = threadIdx.x;
  int base = t * 8;
  int loc[8];
  int s = 0;
#pragma unroll
  for (int i = 0; i < 8; ++i) { loc[i] = s; s += counts[base + i]; }
  sm[t] = s;
  __syncthreads();
  for (int off = 1; off < 1024; off <<= 1) {
    int v = (t >= off) ? sm[t - off] : 0;
    __syncthreads();
    sm[t] += v;
    __syncthreads();
  }
  int excl = (t > 0) ? sm[t - 1] : 0;
#pragma unroll
  for (int i = 0; i < 8; ++i) {
    offsets[base + i] = excl + loc[i];
    int c = counts[base + i];
    deg_inv[base + i] = 1.0f / (float)(c > 0 ? c : 1);
  }
  if (t == 1023) offsets[N_NODES] = sm[1023];
}

__global__ void prep2_kernel(const int* __restrict__ ei, const float* __restrict__ ea,
                             const int* __restrict__ offsets, int* __restrict__ cursor,
                             int* __restrict__ csr_src, float2* __restrict__ csr_ea,
                             const int* __restrict__ batch, int* __restrict__ gstart) {
  const int bb = blockIdx.x;
  if (bb < 512) {
    int e = bb * 256 + threadIdx.x;
    int d = ei[N_EDGES + e];
    int pos = atomicAdd(&cursor[d], 1);
    int slot = offsets[d] + pos;
    csr_src[slot] = ei[e];
    csr_ea[slot] = make_float2(ea[2 * e], ea[2 * e + 1]);
  } else {
    int n = (bb - 512) * 256 + threadIdx.x;
    int b = batch[n];
    if (n == 0) {
      for (int g = 0; g <= b; ++g) gstart[g] = 0;
    } else {
      int bp = batch[n - 1];
      for (int g = bp + 1; g <= b; ++g) gstart[g] = n;
    }
    if (n == N_NODES - 1) {
      for (int g = b + 1; g <= NGRAPH; ++g) gstart[g] = N_NODES;
    }
  }
}

// ---------------- fused MP half-layer (R3-exact) + last-block epilogue ----------------
// blockIdx = node-group*2 + khalf. Edge/contract phases identical to the
// verified R3 kernel. After writing partial[khalf], the LAST-finishing block
// of each pair (device-scope atomic on flags[group]) runs the epilogue
// (combine halves + bias + root + GRU) in-kernel -> no epilogue dispatches.
// Release: all-threads __threadfence() before the atomic; acquire:
// __threadfence() after observing old==1. No spinning -> no dispatch-order
// dependence. LDS = 36.9 KB -> 4 blocks/CU.
__global__ __launch_bounds__(256, 4) void mp_half_kernel(
    const float* __restrict__ out_cur, const int* __restrict__ offsets,
    const int* __restrict__ csr_src, const float2* __restrict__ csr_ea,
    const float* __restrict__ w1, const float* __restrict__ b1,
    const float* __restrict__ w2, float* __restrict__ partial,
    float* __restrict__ O,
    const float* __restrict__ b2, const float* __restrict__ deg_inv,
    const float* __restrict__ root_w, const float* __restrict__ conv_b,
    const float* __restrict__ gwih, const float* __restrict__ gwhh,
    const float* __restrict__ gbih, const float* __restrict__ gbhh,
    float* __restrict__ out_nxt, int* __restrict__ flags) {
  constexpr int C = 32;
  __shared__ float smem[G_NODES * KHALF * SROW];  // 9216 floats = 36864 B
  float* S = smem;
  float* hidb = smem;                // C*KHALF = 2048 floats (aliases S)
  float* osrcb = smem + C * KHALF;   // C*DIM = 1024 floats
  float* red = smem;                 // 16*257 = 4112 floats (aliases S)
  __shared__ int offs[G_NODES + 1];
  __shared__ int isLast;

  const int t = threadIdx.x;
  const int bb = blockIdx.x;
  const int khalf = bb & 1;
  const int node0 = (bb >> 1) * G_NODES;

  if (t <= G_NODES) offs[t] = offsets[min(node0 + t, N_NODES)];

  // build map: thread = (kg 0..15) x (dg 0..15); owns k0..k0+3, d0..d0+1
  const int kg = t >> 4, dg = t & 15;
  const int k0 = kg * 4, d0 = dg * 2;
  // staging map: edge slot ec (0..31), sub-slice sub (0..7)
  const int ec = t >> 3, sub = t & 7;

  // hoist w1/b1 (loop-invariant per thread)
  float w1x[8], w1y[8], b1v[8];
#pragma unroll
  for (int i = 0; i < 8; ++i) {
    const int kgl = khalf * KHALF + sub * 8 + i;
    w1x[i] = w1[kgl];
    w1y[i] = w1[HID + kgl];
    b1v[i] = b1[kgl];
  }

  float acc[G_NODES][4][2];
#pragma unroll
  for (int g = 0; g < G_NODES; ++g)
#pragma unroll
    for (int i = 0; i < 4; ++i) { acc[g][i][0] = 0.0f; acc[g][i][1] = 0.0f; }
  float oacc[G_NODES] = {};
  __syncthreads();

#pragma unroll
  for (int g = 0; g < G_NODES; ++g) {
    const int base = offs[g], end = offs[g + 1];
    for (int c0 = base; c0 < end; c0 += C) {
      const int cnt = min(C, end - c0);
      __syncthreads();  // previous chunk's readers done
      if (ec < cnt) {
        const int slot = c0 + ec;
        const float2 eav = csr_ea[slot];
        const int sidx = csr_src[slot];
        float hv[8];
#pragma unroll
        for (int i = 0; i < 8; ++i)
          hv[i] = fmaxf(fmaf(eav.y, w1y[i], fmaf(eav.x, w1x[i], b1v[i])), 0.0f);
        *(float4*)(hidb + ec * KHALF + sub * 8) =
            make_float4(hv[0], hv[1], hv[2], hv[3]);
        *(float4*)(hidb + ec * KHALF + sub * 8 + 4) =
            make_float4(hv[4], hv[5], hv[6], hv[7]);
        *(float4*)(osrcb + ec * DIM + sub * 4) =
            *(const float4*)(out_cur + sidx * DIM + sub * 4);
      }
      __syncthreads();
      for (int e = 0; e < cnt; ++e) {
        const float4 hvv = *(const float4*)(hidb + e * KHALF + k0);
        const float2 ov = *(const float2*)(osrcb + e * DIM + d0);
        acc[g][0][0] = fmaf(hvv.x, ov.x, acc[g][0][0]);
        acc[g][0][1] = fmaf(hvv.x, ov.y, acc[g][0][1]);
        acc[g][1][0] = fmaf(hvv.y, ov.x, acc[g][1][0]);
        acc[g][1][1] = fmaf(hvv.y, ov.y, acc[g][1][1]);
        acc[g][2][0] = fmaf(hvv.z, ov.x, acc[g][2][0]);
        acc[g][2][1] = fmaf(hvv.z, ov.y, acc[g][2][1]);
        acc[g][3][0] = fmaf(hvv.w, ov.x, acc[g][3][0]);
        acc[g][3][1] = fmaf(hvv.w, ov.y, acc[g][3][1]);
        if (khalf == 0 && t < DIM) oacc[g] += osrcb[e * DIM + t];
      }
    }
  }
  __syncthreads();  // staging dead everywhere; safe to overwrite with S

  // dump S tiles (swizzled): row kl, cols (d0 + (kg&3)*8) & 31
  {
    const int shift = (kg & 3) * 8;
    const int dd = (d0 + shift) & 31;
#pragma unroll
    for (int g = 0; g < G_NODES; ++g) {
      float* Sg = S + g * KHALF * SROW;
#pragma unroll
      for (int i = 0; i < 4; ++i)
        *(float2*)(Sg + (k0 + i) * SROW + dd) = make_float2(acc[g][i][0], acc[g][i][1]);
    }
  }
  if (khalf == 0 && t < DIM) {
#pragma unroll
    for (int g = 0; g < G_NODES; ++g) {
      const int node = node0 + g;
      if (node < N_NODES) O[node * DIM + t] = oacc[g];
    }
  }
  __syncthreads();

  // contract: thread = (ks 0..15, dvh 0..1, og 0..7)
  {
    const int ks = t >> 4;
    const int dvh = (t >> 3) & 1;
    const int og = t & 7;
    const int shift = (ks & 3) * 8;
    float a4[G_NODES][4];
#pragma unroll
    for (int g = 0; g < G_NODES; ++g)
#pragma unroll
      for (int r = 0; r < 4; ++r) a4[g][r] = 0.0f;
#pragma unroll
    for (int i = 0; i < 4; ++i) {
      const int kl = ks * 4 + i;
      const float* w2k = w2 + (size_t)(khalf * KHALF + kl) * (DIM * DIM);
#pragma unroll
      for (int q = 0; q < 4; ++q) {
        const int dbase = dvh * 16 + q * 4;
        const int dq = (dbase + shift) & 31;
        const float4 sv0 = *(const float4*)(S + 0 * KHALF * SROW + kl * SROW + dq);
        const float4 sv1 = *(const float4*)(S + 1 * KHALF * SROW + kl * SROW + dq);
        const float4 sv2 = *(const float4*)(S + 2 * KHALF * SROW + kl * SROW + dq);
        const float4 sv3 = *(const float4*)(S + 3 * KHALF * SROW + kl * SROW + dq);
        const float* s0 = (const float*)&sv0;
        const float* s1 = (const float*)&sv1;
        const float* s2 = (const float*)&sv2;
        const float* s3 = (const float*)&sv3;
#pragma unroll
        for (int r = 0; r < 4; ++r) {
          const float4 wv = *(const float4*)(w2k + (dbase + r) * DIM + og * 4);
          a4[0][0] = fmaf(s0[r], wv.x, a4[0][0]);
          a4[0][1] = fmaf(s0[r], wv.y, a4[0][1]);
          a4[0][2] = fmaf(s0[r], wv.z, a4[0][2]);
          a4[0][3] = fmaf(s0[r], wv.w, a4[0][3]);
          a4[1][0] = fmaf(s1[r], wv.x, a4[1][0]);
          a4[1][1] = fmaf(s1[r], wv.y, a4[1][1]);
          a4[1][2] = fmaf(s1[r], wv.z, a4[1][2]);
          a4[1][3] = fmaf(s1[r], wv.w, a4[1][3]);
          a4[2][0] = fmaf(s2[r], wv.x, a4[2][0]);
          a4[2][1] = fmaf(s2[r], wv.y, a4[2][1]);
          a4[2][2] = fmaf(s2[r], wv.z, a4[2][2]);
          a4[2][3] = fmaf(s2[r], wv.w, a4[2][3]);
          a4[3][0] = fmaf(s3[r], wv.x, a4[3][0]);
          a4[3][1] = fmaf(s3[r], wv.y, a4[3][1]);
          a4[3][2] = fmaf(s3[r], wv.z, a4[3][2]);
          a4[3][3] = fmaf(s3[r], wv.w, a4[3][3]);
        }
      }
    }
    __syncthreads();  // all S reads done; red may alias S
#pragma unroll
    for (int g = 0; g < G_NODES; ++g)
#pragma unroll
      for (int r = 0; r < 4; ++r) red[(g * 4 + r) * 257 + t] = a4[g][r];
  }
  __syncthreads();
  // reduce 32 (ks,dvh) contributions per (g,o) cell and write partial
  if (t < G_NODES * DIM) {
    const int g = t >> 5, o = t & 31;
    const int og = o >> 2, r = o & 3;
    const float* rp = red + (g * 4 + r) * 257 + og;
    float sum = 0.0f;
#pragma unroll
    for (int j = 0; j < 32; ++j) sum += rp[j * 8];
    partial[(size_t)khalf * N_NODES * DIM + (node0 + g) * DIM + o] = sum;
  }

  // ---- fused epilogue: last-finishing half-block of the pair runs it ----
  __threadfence();   // release: make this block's partial/O visible (device scope)
  __syncthreads();
  if (t == 0) isLast = (atomicAdd(&flags[bb >> 1], 1) == 1);
  __syncthreads();
  if (!isLast) return;
  __threadfence();   // acquire: see sibling block's partial/O

  float* ob  = smem + 4352;   // 128 floats (past red's 4112)
  float* hb  = smem + 4480;   // 128
  float* mb  = smem + 4608;   // 128
  float* b2s = smem + 4736;   // 1024 (ends 5760 <= 9216)
  if (t < G_NODES * DIM) {
    hb[t] = out_cur[node0 * DIM + t];
    ob[t] = O[node0 * DIM + t];
  }
#pragma unroll
  for (int i = 0; i < 4; ++i) b2s[i * 256 + t] = b2[i * 256 + t];
  __syncthreads();
  if (t < G_NODES * DIM) {
    const int g = t >> 5, o = t & 31;
    const int node = node0 + g;
    float agg = partial[node * DIM + o] +
                partial[(size_t)N_NODES * DIM + node * DIM + o];
#pragma unroll
    for (int d = 0; d < DIM; ++d) agg = fmaf(ob[g * DIM + d], b2s[d * DIM + o], agg);
    agg *= deg_inv[node];
    float rt = conv_b[o];
#pragma unroll
    for (int d = 0; d < DIM; ++d) rt = fmaf(hb[g * DIM + d], root_w[d * DIM + o], rt);
    mb[t] = fmaxf(agg + rt, 0.0f);
  }
  __syncthreads();
  if (t < G_NODES * DIM) {
    const int g = t >> 5, o = t & 31;
    float gi[3], gh[3];
#pragma unroll
    for (int jj = 0; jj < 3; ++jj) {
      float si = gbih[jj * DIM + o], sh = gbhh[jj * DIM + o];
#pragma unroll
      for (int d = 0; d < DIM; ++d) {
        si = fmaf(mb[g * DIM + d], gwih[d * 3 * DIM + jj * DIM + o], si);
        sh = fmaf(hb[g * DIM + d], gwhh[d * 3 * DIM + jj * DIM + o], sh);
      }
      gi[jj] = si;
      gh[jj] = sh;
    }
    const float r = sigmoidf_(gi[0] + gh[0]);
    const float z = sigmoidf_(gi[1] + gh[1]);
    const float nn = tanhf(fmaf(r, gh[2], gi[2]));
    out_nxt[node0 * DIM + t] = (1.0f - z) * nn + z * hb[t];
  }
}

// ---------------- Set2Set + head (R3-verified) ----------------
__global__ __launch_bounds__(256) void s2s_kernel(
    const float* __restrict__ outf, const int* __restrict__ gstart,
    const float* __restrict__ wih, const float* __restrict__ whh,
    const float* __restrict__ bih, const float* __restrict__ bhh,
    const float* __restrict__ l1w, const float* __restrict__ l1b,
    const float* __restrict__ l2w, const float* __restrict__ l2b,
    float* __restrict__ y) {
  __shared__ float qh[DIM], qc[DIM], qstar[2 * DIM], gates[4 * DIM];
  __shared__ float wsum[4], wmax[4], wr[4][DIM];
  const int b = blockIdx.x, t = threadIdx.x;
  const int gs = gstart[b], ge = gstart[b + 1];
  const int w = t >> 6, lane = t & 63;
  if (t < DIM) { qh[t] = 0.0f; qc[t] = 0.0f; }
  if (t < 2 * DIM) qstar[t] = 0.0f;
  __syncthreads();
  for (int step = 0; step < 3; ++step) {
    if (t < 4 * DIM) {
      float gv = bih[t] + bhh[t];
      for (int i = 0; i < 2 * DIM; ++i) gv = fmaf(qstar[i], wih[i * 4 * DIM + t], gv);
      for (int i = 0; i < DIM; ++i) gv = fmaf(qh[i], whh[i * 4 * DIM + t], gv);
      gates[t] = gv;
    }
    __syncthreads();
    if (t < DIM) {
      const float ig = sigmoidf_(gates[t]);
      const float fg = sigmoidf_(gates[DIM + t]);
      const float gg = tanhf(gates[2 * DIM + t]);
      const float og = sigmoidf_(gates[3 * DIM + t]);
      const float c = fmaf(fg, qc[t], ig * gg);
      qc[t] = c;
      qh[t] = og * tanhf(c);
    }
    __syncthreads();
    float lmax = -INFINITY;
    for (int n = gs + t; n < ge; n += 256) {
      const float* orow = outf + n * DIM;
      float e = 0.0f;
#pragma unroll
      for (int d = 0; d < DIM; ++d) e = fmaf(orow[d], qh[d], e);
      lmax = fmaxf(lmax, e);
    }
#pragma unroll
    for (int off = 32; off > 0; off >>= 1) lmax = fmaxf(lmax, __shfl_xor(lmax, off));
    if (lane == 0) wmax[w] = lmax;
    __syncthreads();
    const float gmax = fmaxf(fmaxf(wmax[0], wmax[1]), fmaxf(wmax[2], wmax[3]));
    float rl[DIM];
#pragma unroll
    for (int d = 0; d < DIM; ++d) rl[d] = 0.0f;
    float lsum = 0.0f;
    for (int n = gs + t; n < ge; n += 256) {
      const float* orow = outf + n * DIM;
      float e = 0.0f;
#pragma unroll
      for (int d = 0; d < DIM; ++d) e = fmaf(orow[d], qh[d], e);
      const float a = expf(e - gmax);
      lsum += a;
#pragma unroll
      for (int d = 0; d < DIM; ++d) rl[d] = fmaf(a, orow[d], rl[d]);
    }
#pragma unroll
    for (int off = 32; off > 0; off >>= 1) {
      lsum += __shfl_xor(lsum, off);
#pragma unroll
      for (int d = 0; d < DIM; ++d) rl[d] += __shfl_xor(rl[d], off);
    }
    __syncthreads();
    if (lane == 0) {
      wsum[w] = lsum;
#pragma unroll
      for (int d = 0; d < DIM; ++d) wr[w][d] = rl[d];
    }
    __syncthreads();
    if (t < DIM) {
      const float stot = wsum[0] + wsum[1] + wsum[2] + wsum[3];
      const float rv = wr[0][t] + wr[1][t] + wr[2][t] + wr[3][t];
      qstar[t] = qh[t];
      qstar[DIM + t] = (stot > 0.0f) ? rv / stot : 0.0f;
    }
    __syncthreads();
  }
  if (t < DIM) {
    float u = l1b[t];
    for (int i = 0; i < 2 * DIM; ++i) u = fmaf(qstar[i], l1w[i * DIM + t], u);
    u = fmaxf(u, 0.0f);
    float v = u * l2w[t];
#pragma unroll
    for (int off = 16; off > 0; off >>= 1) v += __shfl_xor(v, off);
    if (t == 0) y[b] = v + l2b[0];
  }
}

extern "C" void kernel_launch(void* const* d_in, const int* in_sizes, int n_in,
                              void* d_out, int out_size, void* d_ws, size_t ws_size,
                              hipStream_t stream) {
  const float* x        = (const float*)d_in[0];
  const float* ea       = (const float*)d_in[1];
  const float* lin0_w   = (const float*)d_in[2];
  const float* lin0_b   = (const float*)d_in[3];
  const float* enn_w1   = (const float*)d_in[4];
  const float* enn_b1   = (const float*)d_in[5];
  const float* enn_w2   = (const float*)d_in[6];
  const float* enn_b2   = (const float*)d_in[7];
  const float* root_w   = (const float*)d_in[8];
  const float* conv_b   = (const float*)d_in[9];
  const float* gru_wih  = (const float*)d_in[10];
  const float* gru_whh  = (const float*)d_in[11];
  const float* gru_bih  = (const float*)d_in[12];
  const float* gru_bhh  = (const float*)d_in[13];
  const float* s2s_wih  = (const float*)d_in[14];
  const float* s2s_whh  = (const float*)d_in[15];
  const float* s2s_bih  = (const float*)d_in[16];
  const float* s2s_bhh  = (const float*)d_in[17];
  const float* lin1_w   = (const float*)d_in[18];
  const float* lin1_b   = (const float*)d_in[19];
  const float* lin2_w   = (const float*)d_in[20];
  const float* lin2_b   = (const float*)d_in[21];
  const int*   ei       = (const int*)d_in[22];
  const int*   batch    = (const int*)d_in[23];
  float* y = (float*)d_out;

  char* p = (char*)d_ws;
  auto alloc = [&](size_t bytes) -> void* {
    void* r = (void*)p;
    p += (bytes + 255) & ~(size_t)255;
    return r;
  };
  float*  out_a   = (float*)alloc(N_NODES * DIM * 4);
  float*  out_b   = (float*)alloc(N_NODES * DIM * 4);
  int*    counts  = (int*)alloc(N_NODES * 4);
  int*    offsets = (int*)alloc((N_NODES + 1) * 4);
  int*    cursor  = (int*)alloc(N_NODES * 4);
  int*    csr_src = (int*)alloc(N_EDGES * 4);
  float2* csr_ea  = (float2*)alloc(N_EDGES * 8);
  float*  deg_inv = (float*)alloc(N_NODES * 4);
  int*    gstart  = (int*)alloc((NGRAPH + 1) * 4);
  float*  Obuf    = (float*)alloc((size_t)N_NODES * DIM * 4);
  float*  partial = (float*)alloc((size_t)2 * N_NODES * DIM * 4);  // 2 MB
  int*    flags   = (int*)alloc(3 * (N_NODES / G_NODES) * 4);      // per-layer group flags
  (void)ws_size; (void)n_in; (void)in_sizes; (void)out_size;

  hipMemsetAsync(counts, 0, N_NODES * 4, stream);
  hipMemsetAsync(cursor, 0, N_NODES * 4, stream);
  hipMemsetAsync(flags, 0, 3 * (N_NODES / G_NODES) * 4, stream);

  prep1_kernel<<<1024 + 512, 256, 0, stream>>>(x, lin0_w, lin0_b, out_a,
                                               ei + N_EDGES, counts);
  scan_kernel<<<1, 1024, 0, stream>>>(counts, offsets, deg_inv);
  prep2_kernel<<<512 + 32, 256, 0, stream>>>(ei, ea, offsets, cursor, csr_src,
                                             csr_ea, batch, gstart);

  const int ngroups = N_NODES / G_NODES;  // 2048
  const float* cur = out_a;
  float* nxt = out_b;
  for (int layer = 0; layer < 3; ++layer) {
    mp_half_kernel<<<ngroups * 2, 256, 0, stream>>>(
        cur, offsets, csr_src, csr_ea, enn_w1, enn_b1, enn_w2, partial, Obuf,
        enn_b2, deg_inv, root_w, conv_b, gru_wih, gru_whh, gru_bih, gru_bhh,
        nxt, flags + layer * ngroups);
    const float* tmp = cur; cur = nxt; nxt = (float*)tmp;
  }

  s2s_kernel<<<NGRAPH, 256, 0, stream>>>(cur, gstart, s2s_wih, s2s_whh, s2s_bih,
                                         s2s_bhh, lin1_w, lin1_b, lin2_w, lin2_b, y);
}

// Round 12
// 557.076 us; speedup vs baseline: 4.2182x; 4.2182x over previous
//
#include <hip/hip_runtime.h>

#define N_NODES 8192
#define N_EDGES 131072
#define NGRAPH  64
#define DIM     32
#define HID     128
#define KFULL   128
#define KHALF   64
#define G_NODES 4          // nodes per block (8192/4 = 2048 blocks)
#define SROW    36         // S d-stride: 16B-aligned; +swizzle for bank spread

__device__ __forceinline__ float sigmoidf_(float x) { return 1.0f / (1.0f + expf(-x)); }

// ---------------- prep (R3-verified) ----------------
__global__ void prep1_kernel(const float* __restrict__ x, const float* __restrict__ w,
                             const float* __restrict__ b, float* __restrict__ out,
                             const int* __restrict__ dst, int* __restrict__ counts) {
  const int bb = blockIdx.x;
  if (bb < 1024) {
    int idx = bb * 256 + threadIdx.x;
    int n = idx >> 5, d = idx & 31;
    out[idx] = fmaxf(fmaf(x[n], w[d], b[d]), 0.0f);
  } else {
    int e = (bb - 1024) * 256 + threadIdx.x;
    atomicAdd(&counts[dst[e]], 1);
  }
}

__global__ void scan_kernel(const int* __restrict__ counts,
                            int* __restrict__ offsets,
                            float* __restrict__ deg_inv) {
  __shared__ int sm[1024];
  int t = threadIdx.x;
  int base = t * 8;
  int loc[8];
  int s = 0;
#pragma unroll
  for (int i = 0; i < 8; ++i) { loc[i] = s; s += counts[base + i]; }
  sm[t] = s;
  __syncthreads();
  for (int off = 1; off < 1024; off <<= 1) {
    int v = (t >= off) ? sm[t - off] : 0;
    __syncthreads();
    sm[t] += v;
    __syncthreads();
  }
  int excl = (t > 0) ? sm[t - 1] : 0;
#pragma unroll
  for (int i = 0; i < 8; ++i) {
    offsets[base + i] = excl + loc[i];
    int c = counts[base + i];
    deg_inv[base + i] = 1.0f / (float)(c > 0 ? c : 1);
  }
  if (t == 1023) offsets[N_NODES] = sm[1023];
}

__global__ void prep2_kernel(const int* __restrict__ ei, const float* __restrict__ ea,
                             const int* __restrict__ offsets, int* __restrict__ cursor,
                             int* __restrict__ csr_src, float2* __restrict__ csr_ea,
                             const int* __restrict__ batch, int* __restrict__ gstart) {
  const int bb = blockIdx.x;
  if (bb < 512) {
    int e = bb * 256 + threadIdx.x;
    int d = ei[N_EDGES + e];
    int pos = atomicAdd(&cursor[d], 1);
    int slot = offsets[d] + pos;
    csr_src[slot] = ei[e];
    csr_ea[slot] = make_float2(ea[2 * e], ea[2 * e + 1]);
  } else {
    int n = (bb - 512) * 256 + threadIdx.x;
    int b = batch[n];
    if (n == 0) {
      for (int g = 0; g <= b; ++g) gstart[g] = 0;
    } else {
      int bp = batch[n - 1];
      for (int g = bp + 1; g <= b; ++g) gstart[g] = n;
    }
    if (n == N_NODES - 1) {
      for (int g = b + 1; g <= NGRAPH; ++g) gstart[g] = N_NODES;
    }
  }
}

// ---------------- fused MP layer: full-K edge loop, TWO-PASS contract, in-kernel epilogue ----------------
// One block per 4-node group (2048 blocks). Edge loop = R10-verified full-K
// staging (each edge staged once). Dump+contract run twice over a HALF-K S
// buffer (4x64x36 = 36.9 KB, the R3 footprint -> 4 blocks/CU), pass p
// covering k in [p*64, p*64+64) with w2 offset p*64; a4 accumulates across
// passes. Epilogue (bias/root/GRU) = R10/R11-verified body, in-kernel, no
// fences, no partial/O round-trip. LDS = 36864 B.
__global__ __launch_bounds__(256, 4) void mp_layer_kernel(
    const float* __restrict__ out_cur, const int* __restrict__ offsets,
    const int* __restrict__ csr_src, const float2* __restrict__ csr_ea,
    const float* __restrict__ w1, const float* __restrict__ b1,
    const float* __restrict__ w2, const float* __restrict__ b2,
    const float* __restrict__ deg_inv, const float* __restrict__ root_w,
    const float* __restrict__ conv_b, const float* __restrict__ gwih,
    const float* __restrict__ gwhh, const float* __restrict__ gbih,
    const float* __restrict__ gbhh, float* __restrict__ out_nxt) {
  constexpr int C = 32;
  __shared__ float smem[G_NODES * KHALF * SROW];  // 9216 floats = 36864 B
  float* S = smem;
  float* hidb = smem;                  // C*KFULL = 4096 floats (aliases S)
  float* osrcb = smem + C * KFULL;     // C*DIM = 1024 floats (ends 5120 <= 9216)
  float* red = smem;                   // 16*257 = 4112 floats (aliases S)
  float* ob  = smem + 4352;            // 128 floats
  float* hb  = smem + 4480;            // 128
  float* mb  = smem + 4608;            // 128
  float* b2s = smem + 4736;            // 1024 (ends 5760 <= 9216)
  __shared__ int offs[G_NODES + 1];

  const int t = threadIdx.x;
  const int node0 = blockIdx.x * G_NODES;

  if (t <= G_NODES) offs[t] = offsets[node0 + t];

  // edge-compute map: (kg 0..31) x (dg 0..7); owns k0..k0+3 (of 128), d0..d0+3
  const int kg = t >> 3, dg = t & 7;
  const int k0 = kg * 4, d0 = dg * 4;
  // staging map: edge slot ec (0..31), sub (0..7) covers k = sub*16 .. sub*16+15
  const int ec = t >> 3, sub = t & 7;

  // hoist w1/b1 (16 k per staging thread)
  float w1x[16], w1y[16], b1v[16];
#pragma unroll
  for (int i = 0; i < 16; ++i) {
    const int kgl = sub * 16 + i;
    w1x[i] = w1[kgl];
    w1y[i] = w1[HID + kgl];
    b1v[i] = b1[kgl];
  }

  float acc[G_NODES][4][4];
#pragma unroll
  for (int g = 0; g < G_NODES; ++g)
#pragma unroll
    for (int i = 0; i < 4; ++i)
#pragma unroll
      for (int j = 0; j < 4; ++j) acc[g][i][j] = 0.0f;
  float oacc[G_NODES] = {};
  __syncthreads();  // offs visible

#pragma unroll
  for (int g = 0; g < G_NODES; ++g) {
    const int base = offs[g], end = offs[g + 1];
    for (int c0 = base; c0 < end; c0 += C) {
      const int cnt = min(C, end - c0);
      __syncthreads();  // previous chunk's readers done
      if (ec < cnt) {
        const int slot = c0 + ec;
        const float2 eav = csr_ea[slot];
        const int sidx = csr_src[slot];
        float hv[16];
#pragma unroll
        for (int i = 0; i < 16; ++i)
          hv[i] = fmaxf(fmaf(eav.y, w1y[i], fmaf(eav.x, w1x[i], b1v[i])), 0.0f);
#pragma unroll
        for (int j = 0; j < 4; ++j)
          *(float4*)(hidb + ec * KFULL + sub * 16 + j * 4) =
              make_float4(hv[j * 4], hv[j * 4 + 1], hv[j * 4 + 2], hv[j * 4 + 3]);
        *(float4*)(osrcb + ec * DIM + sub * 4) =
            *(const float4*)(out_cur + sidx * DIM + sub * 4);
      }
      __syncthreads();
      for (int e = 0; e < cnt; ++e) {
        const float4 hvv = *(const float4*)(hidb + e * KFULL + k0);
        const float4 ov = *(const float4*)(osrcb + e * DIM + d0);
        acc[g][0][0] = fmaf(hvv.x, ov.x, acc[g][0][0]);
        acc[g][0][1] = fmaf(hvv.x, ov.y, acc[g][0][1]);
        acc[g][0][2] = fmaf(hvv.x, ov.z, acc[g][0][2]);
        acc[g][0][3] = fmaf(hvv.x, ov.w, acc[g][0][3]);
        acc[g][1][0] = fmaf(hvv.y, ov.x, acc[g][1][0]);
        acc[g][1][1] = fmaf(hvv.y, ov.y, acc[g][1][1]);
        acc[g][1][2] = fmaf(hvv.y, ov.z, acc[g][1][2]);
        acc[g][1][3] = fmaf(hvv.y, ov.w, acc[g][1][3]);
        acc[g][2][0] = fmaf(hvv.z, ov.x, acc[g][2][0]);
        acc[g][2][1] = fmaf(hvv.z, ov.y, acc[g][2][1]);
        acc[g][2][2] = fmaf(hvv.z, ov.z, acc[g][2][2]);
        acc[g][2][3] = fmaf(hvv.z, ov.w, acc[g][2][3]);
        acc[g][3][0] = fmaf(hvv.w, ov.x, acc[g][3][0]);
        acc[g][3][1] = fmaf(hvv.w, ov.y, acc[g][3][1]);
        acc[g][3][2] = fmaf(hvv.w, ov.z, acc[g][3][2]);
        acc[g][3][3] = fmaf(hvv.w, ov.w, acc[g][3][3]);
        if (t < DIM) oacc[g] += osrcb[e * DIM + t];
      }
    }
  }
  __syncthreads();  // staging dead; S region reusable

  // ---- two-pass dump + contract over half-K S buffer ----
  const int ks = t >> 4;          // contract map: (ks 0..15, dvh 0..1, og 0..7)
  const int dvh = (t >> 3) & 1;
  const int og = t & 7;
  float a4[G_NODES][4];
#pragma unroll
  for (int g = 0; g < G_NODES; ++g)
#pragma unroll
    for (int r = 0; r < 4; ++r) a4[g][r] = 0.0f;

#pragma unroll
  for (int p = 0; p < 2; ++p) {
    // dump rows k in [p*64, p*64+64): threads with kg>>4 == p
    if ((kg >> 4) == p) {
      const int kgl4 = (kg & 15) * 4;         // local row base 0..60
      const int shift = (kg & 3) * 8;         // == ((local row)>>2 & 3)*8
      const int dd = (d0 + shift) & 31;
#pragma unroll
      for (int g = 0; g < G_NODES; ++g) {
        float* Sg = S + g * KHALF * SROW;
#pragma unroll
        for (int i = 0; i < 4; ++i)
          *(float4*)(Sg + (kgl4 + i) * SROW + dd) =
              make_float4(acc[g][i][0], acc[g][i][1], acc[g][i][2], acc[g][i][3]);
      }
    }
    __syncthreads();
    // contract local rows 0..63 with w2 offset p*64 (R3-exact body)
#pragma unroll
    for (int i = 0; i < 4; ++i) {
      const int kl = ks * 4 + i;
      const int shift = (ks & 3) * 8;
      const float* w2k = w2 + (size_t)(p * KHALF + kl) * (DIM * DIM);
#pragma unroll
      for (int q = 0; q < 4; ++q) {
        const int dbase = dvh * 16 + q * 4;
        const int dq = (dbase + shift) & 31;
        const int soff = kl * SROW + dq;
        const float4 sv0 = *(const float4*)(S + 0 * KHALF * SROW + soff);
        const float4 sv1 = *(const float4*)(S + 1 * KHALF * SROW + soff);
        const float4 sv2 = *(const float4*)(S + 2 * KHALF * SROW + soff);
        const float4 sv3 = *(const float4*)(S + 3 * KHALF * SROW + soff);
        const float* s0 = (const float*)&sv0;
        const float* s1 = (const float*)&sv1;
        const float* s2 = (const float*)&sv2;
        const float* s3 = (const float*)&sv3;
#pragma unroll
        for (int r = 0; r < 4; ++r) {
          const float4 wv = *(const float4*)(w2k + (dbase + r) * DIM + og * 4);
          a4[0][0] = fmaf(s0[r], wv.x, a4[0][0]);
          a4[0][1] = fmaf(s0[r], wv.y, a4[0][1]);
          a4[0][2] = fmaf(s0[r], wv.z, a4[0][2]);
          a4[0][3] = fmaf(s0[r], wv.w, a4[0][3]);
          a4[1][0] = fmaf(s1[r], wv.x, a4[1][0]);
          a4[1][1] = fmaf(s1[r], wv.y, a4[1][1]);
          a4[1][2] = fmaf(s1[r], wv.z, a4[1][2]);
          a4[1][3] = fmaf(s1[r], wv.w, a4[1][3]);
          a4[2][0] = fmaf(s2[r], wv.x, a4[2][0]);
          a4[2][1] = fmaf(s2[r], wv.y, a4[2][1]);
          a4[2][2] = fmaf(s2[r], wv.z, a4[2][2]);
          a4[2][3] = fmaf(s2[r], wv.w, a4[2][3]);
          a4[3][0] = fmaf(s3[r], wv.x, a4[3][0]);
          a4[3][1] = fmaf(s3[r], wv.y, a4[3][1]);
          a4[3][2] = fmaf(s3[r], wv.z, a4[3][2]);
          a4[3][3] = fmaf(s3[r], wv.w, a4[3][3]);
        }
      }
    }
    __syncthreads();  // S reads done (pass-1 dump / red may overwrite)
  }

  // red write + epilogue input staging (disjoint LDS regions)
#pragma unroll
  for (int g = 0; g < G_NODES; ++g)
#pragma unroll
    for (int r = 0; r < 4; ++r) red[(g * 4 + r) * 257 + t] = a4[g][r];
  if (t < DIM) {
#pragma unroll
    for (int g = 0; g < G_NODES; ++g) ob[g * DIM + t] = oacc[g];
  }
  if (t < G_NODES * DIM) hb[t] = out_cur[node0 * DIM + t];
#pragma unroll
  for (int i = 0; i < 4; ++i) b2s[i * 256 + t] = b2[i * 256 + t];
  __syncthreads();

  // epilogue: reduce red + bias/root -> mb (R10/R11-verified body)
  if (t < G_NODES * DIM) {
    const int g = t >> 5, o = t & 31;
    const int og2 = o >> 2, r2 = o & 3;
    const float* rp = red + (g * 4 + r2) * 257 + og2;
    float agg = 0.0f;
#pragma unroll
    for (int j = 0; j < 32; ++j) agg += rp[j * 8];
#pragma unroll
    for (int d = 0; d < DIM; ++d) agg = fmaf(ob[g * DIM + d], b2s[d * DIM + o], agg);
    agg *= deg_inv[node0 + g];
    float rt = conv_b[o];
#pragma unroll
    for (int d = 0; d < DIM; ++d) rt = fmaf(hb[g * DIM + d], root_w[d * DIM + o], rt);
    mb[t] = fmaxf(agg + rt, 0.0f);
  }
  __syncthreads();
  // GRU
  if (t < G_NODES * DIM) {
    const int g = t >> 5, o = t & 31;
    float gi[3], gh[3];
#pragma unroll
    for (int jj = 0; jj < 3; ++jj) {
      float si = gbih[jj * DIM + o], sh = gbhh[jj * DIM + o];
#pragma unroll
      for (int d = 0; d < DIM; ++d) {
        si = fmaf(mb[g * DIM + d], gwih[d * 3 * DIM + jj * DIM + o], si);
        sh = fmaf(hb[g * DIM + d], gwhh[d * 3 * DIM + jj * DIM + o], sh);
      }
      gi[jj] = si;
      gh[jj] = sh;
    }
    const float r = sigmoidf_(gi[0] + gh[0]);
    const float z = sigmoidf_(gi[1] + gh[1]);
    const float nn = tanhf(fmaf(r, gh[2], gi[2]));
    out_nxt[node0 * DIM + t] = (1.0f - z) * nn + z * hb[t];
  }
}

// ---------------- Set2Set + head (R3-verified) ----------------
__global__ __launch_bounds__(256) void s2s_kernel(
    const float* __restrict__ outf, const int* __restrict__ gstart,
    const float* __restrict__ wih, const float* __restrict__ whh,
    const float* __restrict__ bih, const float* __restrict__ bhh,
    const float* __restrict__ l1w, const float* __restrict__ l1b,
    const float* __restrict__ l2w, const float* __restrict__ l2b,
    float* __restrict__ y) {
  __shared__ float qh[DIM], qc[DIM], qstar[2 * DIM], gates[4 * DIM];
  __shared__ float wsum[4], wmax[4], wr[4][DIM];
  const int b = blockIdx.x, t = threadIdx.x;
  const int gs = gstart[b], ge = gstart[b + 1];
  const int w = t >> 6, lane = t & 63;
  if (t < DIM) { qh[t] = 0.0f; qc[t] = 0.0f; }
  if (t < 2 * DIM) qstar[t] = 0.0f;
  __syncthreads();
  for (int step = 0; step < 3; ++step) {
    if (t < 4 * DIM) {
      float gv = bih[t] + bhh[t];
      for (int i = 0; i < 2 * DIM; ++i) gv = fmaf(qstar[i], wih[i * 4 * DIM + t], gv);
      for (int i = 0; i < DIM; ++i) gv = fmaf(qh[i], whh[i * 4 * DIM + t], gv);
      gates[t] = gv;
    }
    __syncthreads();
    if (t < DIM) {
      const float ig = sigmoidf_(gates[t]);
      const float fg = sigmoidf_(gates[DIM + t]);
      const float gg = tanhf(gates[2 * DIM + t]);
      const float og = sigmoidf_(gates[3 * DIM + t]);
      const float c = fmaf(fg, qc[t], ig * gg);
      qc[t] = c;
      qh[t] = og * tanhf(c);
    }
    __syncthreads();
    float lmax = -INFINITY;
    for (int n = gs + t; n < ge; n += 256) {
      const float* orow = outf + n * DIM;
      float e = 0.0f;
#pragma unroll
      for (int d = 0; d < DIM; ++d) e = fmaf(orow[d], qh[d], e);
      lmax = fmaxf(lmax, e);
    }
#pragma unroll
    for (int off = 32; off > 0; off >>= 1) lmax = fmaxf(lmax, __shfl_xor(lmax, off));
    if (lane == 0) wmax[w] = lmax;
    __syncthreads();
    const float gmax = fmaxf(fmaxf(wmax[0], wmax[1]), fmaxf(wmax[2], wmax[3]));
    float rl[DIM];
#pragma unroll
    for (int d = 0; d < DIM; ++d) rl[d] = 0.0f;
    float lsum = 0.0f;
    for (int n = gs + t; n < ge; n += 256) {
      const float* orow = outf + n * DIM;
      float e = 0.0f;
#pragma unroll
      for (int d = 0; d < DIM; ++d) e = fmaf(orow[d], qh[d], e);
      const float a = expf(e - gmax);
      lsum += a;
#pragma unroll
      for (int d = 0; d < DIM; ++d) rl[d] = fmaf(a, orow[d], rl[d]);
    }
#pragma unroll
    for (int off = 32; off > 0; off >>= 1) {
      lsum += __shfl_xor(lsum, off);
#pragma unroll
      for (int d = 0; d < DIM; ++d) rl[d] += __shfl_xor(rl[d], off);
    }
    __syncthreads();
    if (lane == 0) {
      wsum[w] = lsum;
#pragma unroll
      for (int d = 0; d < DIM; ++d) wr[w][d] = rl[d];
    }
    __syncthreads();
    if (t < DIM) {
      const float stot = wsum[0] + wsum[1] + wsum[2] + wsum[3];
      const float rv = wr[0][t] + wr[1][t] + wr[2][t] + wr[3][t];
      qstar[t] = qh[t];
      qstar[DIM + t] = (stot > 0.0f) ? rv / stot : 0.0f;
    }
    __syncthreads();
  }
  if (t < DIM) {
    float u = l1b[t];
    for (int i = 0; i < 2 * DIM; ++i) u = fmaf(qstar[i], l1w[i * DIM + t], u);
    u = fmaxf(u, 0.0f);
    float v = u * l2w[t];
#pragma unroll
    for (int off = 16; off > 0; off >>= 1) v += __shfl_xor(v, off);
    if (t == 0) y[b] = v + l2b[0];
  }
}

extern "C" void kernel_launch(void* const* d_in, const int* in_sizes, int n_in,
                              void* d_out, int out_size, void* d_ws, size_t ws_size,
                              hipStream_t stream) {
  const float* x        = (const float*)d_in[0];
  const float* ea       = (const float*)d_in[1];
  const float* lin0_w   = (const float*)d_in[2];
  const float* lin0_b   = (const float*)d_in[3];
  const float* enn_w1   = (const float*)d_in[4];
  const float* enn_b1   = (const float*)d_in[5];
  const float* enn_w2   = (const float*)d_in[6];
  const float* enn_b2   = (const float*)d_in[7];
  const float* root_w   = (const float*)d_in[8];
  const float* conv_b   = (const float*)d_in[9];
  const float* gru_wih  = (const float*)d_in[10];
  const float* gru_whh  = (const float*)d_in[11];
  const float* gru_bih  = (const float*)d_in[12];
  const float* gru_bhh  = (const float*)d_in[13];
  const float* s2s_wih  = (const float*)d_in[14];
  const float* s2s_whh  = (const float*)d_in[15];
  const float* s2s_bih  = (const float*)d_in[16];
  const float* s2s_bhh  = (const float*)d_in[17];
  const float* lin1_w   = (const float*)d_in[18];
  const float* lin1_b   = (const float*)d_in[19];
  const float* lin2_w   = (const float*)d_in[20];
  const float* lin2_b   = (const float*)d_in[21];
  const int*   ei       = (const int*)d_in[22];
  const int*   batch    = (const int*)d_in[23];
  float* y = (float*)d_out;

  char* p = (char*)d_ws;
  auto alloc = [&](size_t bytes) -> void* {
    void* r = (void*)p;
    p += (bytes + 255) & ~(size_t)255;
    return r;
  };
  float*  out_a   = (float*)alloc(N_NODES * DIM * 4);
  float*  out_b   = (float*)alloc(N_NODES * DIM * 4);
  int*    counts  = (int*)alloc(N_NODES * 4);   // contiguous with cursor:
  int*    cursor  = (int*)alloc(N_NODES * 4);   // single 64 KB memset below
  int*    offsets = (int*)alloc((N_NODES + 1) * 4);
  int*    csr_src = (int*)alloc(N_EDGES * 4);
  float2* csr_ea  = (float2*)alloc(N_EDGES * 8);
  float*  deg_inv = (float*)alloc(N_NODES * 4);
  int*    gstart  = (int*)alloc((NGRAPH + 1) * 4);
  (void)ws_size; (void)n_in; (void)in_sizes; (void)out_size;

  hipMemsetAsync(counts, 0, 2 * N_NODES * 4, stream);  // counts + cursor

  prep1_kernel<<<1024 + 512, 256, 0, stream>>>(x, lin0_w, lin0_b, out_a,
                                               ei + N_EDGES, counts);
  scan_kernel<<<1, 1024, 0, stream>>>(counts, offsets, deg_inv);
  prep2_kernel<<<512 + 32, 256, 0, stream>>>(ei, ea, offsets, cursor, csr_src,
                                             csr_ea, batch, gstart);

  const int ngroups = N_NODES / G_NODES;  // 2048
  const float* cur = out_a;
  float* nxt = out_b;
  for (int layer = 0; layer < 3; ++layer) {
    mp_layer_kernel<<<ngroups, 256, 0, stream>>>(
        cur, offsets, csr_src, csr_ea, enn_w1, enn_b1, enn_w2, enn_b2,
        deg_inv, root_w, conv_b, gru_wih, gru_whh, gru_bih, gru_bhh, nxt);
    const float* tmp = cur; cur = nxt; nxt = (float*)tmp;
  }

  s2s_kernel<<<NGRAPH, 256, 0, stream>>>(cur, gstart, s2s_wih, s2s_whh, s2s_bih,
                                         s2s_bhh, lin1_w, lin1_b, lin2_w, lin2_b, y);
}

// Round 13
// 426.171 us; speedup vs baseline: 5.5139x; 1.3072x over previous
//
#include <hip/hip_runtime.h>

#define N_NODES 8192
#define N_EDGES 131072
#define NGRAPH  64
#define DIM     32
#define HID     128
#define KHALF   64
#define G_NODES 4          // nodes per block (8192/4 = 2048 blocks)
#define SROW    36         // S d-stride: 16B-aligned; +swizzle for bank spread

__device__ __forceinline__ float sigmoidf_(float x) { return 1.0f / (1.0f + expf(-x)); }

// ---------------- prep (R3-verified) ----------------
__global__ void prep1_kernel(const float* __restrict__ x, const float* __restrict__ w,
                             const float* __restrict__ b, float* __restrict__ out,
                             const int* __restrict__ dst, int* __restrict__ counts) {
  const int bb = blockIdx.x;
  if (bb < 1024) {
    int idx = bb * 256 + threadIdx.x;
    int n = idx >> 5, d = idx & 31;
    out[idx] = fmaxf(fmaf(x[n], w[d], b[d]), 0.0f);
  } else {
    int e = (bb - 1024) * 256 + threadIdx.x;
    atomicAdd(&counts[dst[e]], 1);
  }
}

__global__ void scan_kernel(const int* __restrict__ counts,
                            int* __restrict__ offsets,
                            float* __restrict__ deg_inv) {
  __shared__ int sm[1024];
  int t = threadIdx.x;
  int base = t * 8;
  int loc[8];
  int s = 0;
#pragma unroll
  for (int i = 0; i < 8; ++i) { loc[i] = s; s += counts[base + i]; }
  sm[t] = s;
  __syncthreads();
  for (int off = 1; off < 1024; off <<= 1) {
    int v = (t >= off) ? sm[t - off] : 0;
    __syncthreads();
    sm[t] += v;
    __syncthreads();
  }
  int excl = (t > 0) ? sm[t - 1] : 0;
#pragma unroll
  for (int i = 0; i < 8; ++i) {
    offsets[base + i] = excl + loc[i];
    int c = counts[base + i];
    deg_inv[base + i] = 1.0f / (float)(c > 0 ? c : 1);
  }
  if (t == 1023) offsets[N_NODES] = sm[1023];
}

__global__ void prep2_kernel(const int* __restrict__ ei, const float* __restrict__ ea,
                             const int* __restrict__ offsets, int* __restrict__ cursor,
                             int* __restrict__ csr_src, float2* __restrict__ csr_ea,
                             const int* __restrict__ batch, int* __restrict__ gstart) {
  const int bb = blockIdx.x;
  if (bb < 512) {
    int e = bb * 256 + threadIdx.x;
    int d = ei[N_EDGES + e];
    int pos = atomicAdd(&cursor[d], 1);
    int slot = offsets[d] + pos;
    csr_src[slot] = ei[e];
    csr_ea[slot] = make_float2(ea[2 * e], ea[2 * e + 1]);
  } else {
    int n = (bb - 512) * 256 + threadIdx.x;
    int b = batch[n];
    if (n == 0) {
      for (int g = 0; g <= b; ++g) gstart[g] = 0;
    } else {
      int bp = batch[n - 1];
      for (int g = bp + 1; g <= b; ++g) gstart[g] = n;
    }
    if (n == N_NODES - 1) {
      for (int g = b + 1; g <= NGRAPH; ++g) gstart[g] = N_NODES;
    }
  }
}

// ---------------- fused MP layer: TWO k-half passes (edge loop + dump + contract
// per pass, all R3-exact bodies), then in-kernel epilogue (R12-verified). ----------
// One block per 4-node group (2048 blocks). Per pass p: R3's khalf=p edge loop
// (acc = 32 floats/thread, the R3 register footprint), dump S, contract with
// w2 offset p*64, accumulating a4 across passes. No partial/O round-trip, no
// fences, no epilogue dispatches. LDS = 36864 B. launch_bounds(256,3) relaxes
// the VGPR cap (~170) to avoid R12's spill; at <=128 VGPR HW still gives
// 4 blocks/CU (LDS-capped).
__global__ __launch_bounds__(256, 3) void mp_layer_kernel(
    const float* __restrict__ out_cur, const int* __restrict__ offsets,
    const int* __restrict__ csr_src, const float2* __restrict__ csr_ea,
    const float* __restrict__ w1, const float* __restrict__ b1,
    const float* __restrict__ w2, const float* __restrict__ b2,
    const float* __restrict__ deg_inv, const float* __restrict__ root_w,
    const float* __restrict__ conv_b, const float* __restrict__ gwih,
    const float* __restrict__ gwhh, const float* __restrict__ gbih,
    const float* __restrict__ gbhh, float* __restrict__ out_nxt) {
  constexpr int C = 32;
  __shared__ float smem[G_NODES * KHALF * SROW];  // 9216 floats = 36864 B
  float* S = smem;
  float* hidb = smem;                // C*KHALF = 2048 floats (aliases S)
  float* osrcb = smem + C * KHALF;   // C*DIM = 1024 floats (ends 3072)
  float* red = smem;                 // 16*257 = 4112 floats (aliases S)
  float* ob  = smem + 4352;          // 128 floats
  float* hb  = smem + 4480;          // 128
  float* mb  = smem + 4608;          // 128
  float* b2s = smem + 4736;          // 1024 (ends 5760 <= 9216)
  __shared__ int offs[G_NODES + 1];

  const int t = threadIdx.x;
  const int node0 = blockIdx.x * G_NODES;

  if (t <= G_NODES) offs[t] = offsets[node0 + t];

  // R3-exact maps: (kg 0..15) x (dg 0..15); k0 local 0..60, d0 0..30
  const int kg = t >> 4, dg = t & 15;
  const int k0 = kg * 4, d0 = dg * 2;
  const int ec = t >> 3, sub = t & 7;
  // contract map (R3-exact)
  const int ks = t >> 4;
  const int dvh = (t >> 3) & 1;
  const int og = t & 7;

  float a4[G_NODES][4];
#pragma unroll
  for (int g = 0; g < G_NODES; ++g)
#pragma unroll
    for (int r = 0; r < 4; ++r) a4[g][r] = 0.0f;
  float oacc[G_NODES] = {};
  __syncthreads();  // offs visible

#pragma unroll
  for (int p = 0; p < 2; ++p) {
    // hoist w1/b1 for this k-half (R3-exact, khalf=p)
    float w1x[8], w1y[8], b1v[8];
#pragma unroll
    for (int i = 0; i < 8; ++i) {
      const int kgl = p * KHALF + sub * 8 + i;
      w1x[i] = w1[kgl];
      w1y[i] = w1[HID + kgl];
      b1v[i] = b1[kgl];
    }
    float acc[G_NODES][4][2];
#pragma unroll
    for (int g = 0; g < G_NODES; ++g)
#pragma unroll
      for (int i = 0; i < 4; ++i) { acc[g][i][0] = 0.0f; acc[g][i][1] = 0.0f; }

    // R3-exact edge loop for this half
#pragma unroll
    for (int g = 0; g < G_NODES; ++g) {
      const int base = offs[g], end = offs[g + 1];
      for (int c0 = base; c0 < end; c0 += C) {
        const int cnt = min(C, end - c0);
        __syncthreads();  // previous chunk's readers done / prior-pass S reads done
        if (ec < cnt) {
          const int slot = c0 + ec;
          const float2 eav = csr_ea[slot];
          const int sidx = csr_src[slot];
          float hv[8];
#pragma unroll
          for (int i = 0; i < 8; ++i)
            hv[i] = fmaxf(fmaf(eav.y, w1y[i], fmaf(eav.x, w1x[i], b1v[i])), 0.0f);
          *(float4*)(hidb + ec * KHALF + sub * 8) =
              make_float4(hv[0], hv[1], hv[2], hv[3]);
          *(float4*)(hidb + ec * KHALF + sub * 8 + 4) =
              make_float4(hv[4], hv[5], hv[6], hv[7]);
          *(float4*)(osrcb + ec * DIM + sub * 4) =
              *(const float4*)(out_cur + sidx * DIM + sub * 4);
        }
        __syncthreads();
        for (int e = 0; e < cnt; ++e) {
          const float4 hvv = *(const float4*)(hidb + e * KHALF + k0);
          const float2 ov = *(const float2*)(osrcb + e * DIM + d0);
          acc[g][0][0] = fmaf(hvv.x, ov.x, acc[g][0][0]);
          acc[g][0][1] = fmaf(hvv.x, ov.y, acc[g][0][1]);
          acc[g][1][0] = fmaf(hvv.y, ov.x, acc[g][1][0]);
          acc[g][1][1] = fmaf(hvv.y, ov.y, acc[g][1][1]);
          acc[g][2][0] = fmaf(hvv.z, ov.x, acc[g][2][0]);
          acc[g][2][1] = fmaf(hvv.z, ov.y, acc[g][2][1]);
          acc[g][3][0] = fmaf(hvv.w, ov.x, acc[g][3][0]);
          acc[g][3][1] = fmaf(hvv.w, ov.y, acc[g][3][1]);
          if (p == 0 && t < DIM) oacc[g] += osrcb[e * DIM + t];
        }
      }
    }
    __syncthreads();  // staging dead; safe to overwrite with S

    // dump S tiles (R3-exact swizzle): row kl local, cols (d0 + (kg&3)*8) & 31
    {
      const int shift = (kg & 3) * 8;
      const int dd = (d0 + shift) & 31;
#pragma unroll
      for (int g = 0; g < G_NODES; ++g) {
        float* Sg = S + g * KHALF * SROW;
#pragma unroll
        for (int i = 0; i < 4; ++i)
          *(float2*)(Sg + (k0 + i) * SROW + dd) =
              make_float2(acc[g][i][0], acc[g][i][1]);
      }
    }
    __syncthreads();

    // contract (R3-exact body), w2 offset p*64, accumulate into a4
#pragma unroll
    for (int i = 0; i < 4; ++i) {
      const int kl = ks * 4 + i;
      const int shift = (ks & 3) * 8;
      const float* w2k = w2 + (size_t)(p * KHALF + kl) * (DIM * DIM);
#pragma unroll
      for (int q = 0; q < 4; ++q) {
        const int dbase = dvh * 16 + q * 4;
        const int dq = (dbase + shift) & 31;
        const int soff = kl * SROW + dq;
        const float4 sv0 = *(const float4*)(S + 0 * KHALF * SROW + soff);
        const float4 sv1 = *(const float4*)(S + 1 * KHALF * SROW + soff);
        const float4 sv2 = *(const float4*)(S + 2 * KHALF * SROW + soff);
        const float4 sv3 = *(const float4*)(S + 3 * KHALF * SROW + soff);
        const float* s0 = (const float*)&sv0;
        const float* s1 = (const float*)&sv1;
        const float* s2 = (const float*)&sv2;
        const float* s3 = (const float*)&sv3;
#pragma unroll
        for (int r = 0; r < 4; ++r) {
          const float4 wv = *(const float4*)(w2k + (dbase + r) * DIM + og * 4);
          a4[0][0] = fmaf(s0[r], wv.x, a4[0][0]);
          a4[0][1] = fmaf(s0[r], wv.y, a4[0][1]);
          a4[0][2] = fmaf(s0[r], wv.z, a4[0][2]);
          a4[0][3] = fmaf(s0[r], wv.w, a4[0][3]);
          a4[1][0] = fmaf(s1[r], wv.x, a4[1][0]);
          a4[1][1] = fmaf(s1[r], wv.y, a4[1][1]);
          a4[1][2] = fmaf(s1[r], wv.z, a4[1][2]);
          a4[1][3] = fmaf(s1[r], wv.w, a4[1][3]);
          a4[2][0] = fmaf(s2[r], wv.x, a4[2][0]);
          a4[2][1] = fmaf(s2[r], wv.y, a4[2][1]);
          a4[2][2] = fmaf(s2[r], wv.z, a4[2][2]);
          a4[2][3] = fmaf(s2[r], wv.w, a4[2][3]);
          a4[3][0] = fmaf(s3[r], wv.x, a4[3][0]);
          a4[3][1] = fmaf(s3[r], wv.y, a4[3][1]);
          a4[3][2] = fmaf(s3[r], wv.z, a4[3][2]);
          a4[3][3] = fmaf(s3[r], wv.w, a4[3][3]);
        }
      }
    }
    __syncthreads();  // S reads done; next pass may overwrite S
  }

  // red write + epilogue input staging (R12-verified, disjoint LDS regions)
#pragma unroll
  for (int g = 0; g < G_NODES; ++g)
#pragma unroll
    for (int r = 0; r < 4; ++r) red[(g * 4 + r) * 257 + t] = a4[g][r];
  if (t < DIM) {
#pragma unroll
    for (int g = 0; g < G_NODES; ++g) ob[g * DIM + t] = oacc[g];
  }
  if (t < G_NODES * DIM) hb[t] = out_cur[node0 * DIM + t];
#pragma unroll
  for (int i = 0; i < 4; ++i) b2s[i * 256 + t] = b2[i * 256 + t];
  __syncthreads();

  // epilogue: reduce red + bias/root -> mb (R12-verified body)
  if (t < G_NODES * DIM) {
    const int g = t >> 5, o = t & 31;
    const int og2 = o >> 2, r2 = o & 3;
    const float* rp = red + (g * 4 + r2) * 257 + og2;
    float agg = 0.0f;
#pragma unroll
    for (int j = 0; j < 32; ++j) agg += rp[j * 8];
#pragma unroll
    for (int d = 0; d < DIM; ++d) agg = fmaf(ob[g * DIM + d], b2s[d * DIM + o], agg);
    agg *= deg_inv[node0 + g];
    float rt = conv_b[o];
#pragma unroll
    for (int d = 0; d < DIM; ++d) rt = fmaf(hb[g * DIM + d], root_w[d * DIM + o], rt);
    mb[t] = fmaxf(agg + rt, 0.0f);
  }
  __syncthreads();
  // GRU (R12-verified body)
  if (t < G_NODES * DIM) {
    const int g = t >> 5, o = t & 31;
    float gi[3], gh[3];
#pragma unroll
    for (int jj = 0; jj < 3; ++jj) {
      float si = gbih[jj * DIM + o], sh = gbhh[jj * DIM + o];
#pragma unroll
      for (int d = 0; d < DIM; ++d) {
        si = fmaf(mb[g * DIM + d], gwih[d * 3 * DIM + jj * DIM + o], si);
        sh = fmaf(hb[g * DIM + d], gwhh[d * 3 * DIM + jj * DIM + o], sh);
      }
      gi[jj] = si;
      gh[jj] = sh;
    }
    const float r = sigmoidf_(gi[0] + gh[0]);
    const float z = sigmoidf_(gi[1] + gh[1]);
    const float nn = tanhf(fmaf(r, gh[2], gi[2]));
    out_nxt[node0 * DIM + t] = (1.0f - z) * nn + z * hb[t];
  }
}

// ---------------- Set2Set + head (R3-verified) ----------------
__global__ __launch_bounds__(256) void s2s_kernel(
    const float* __restrict__ outf, const int* __restrict__ gstart,
    const float* __restrict__ wih, const float* __restrict__ whh,
    const float* __restrict__ bih, const float* __restrict__ bhh,
    const float* __restrict__ l1w, const float* __restrict__ l1b,
    const float* __restrict__ l2w, const float* __restrict__ l2b,
    float* __restrict__ y) {
  __shared__ float qh[DIM], qc[DIM], qstar[2 * DIM], gates[4 * DIM];
  __shared__ float wsum[4], wmax[4], wr[4][DIM];
  const int b = blockIdx.x, t = threadIdx.x;
  const int gs = gstart[b], ge = gstart[b + 1];
  const int w = t >> 6, lane = t & 63;
  if (t < DIM) { qh[t] = 0.0f; qc[t] = 0.0f; }
  if (t < 2 * DIM) qstar[t] = 0.0f;
  __syncthreads();
  for (int step = 0; step < 3; ++step) {
    if (t < 4 * DIM) {
      float gv = bih[t] + bhh[t];
      for (int i = 0; i < 2 * DIM; ++i) gv = fmaf(qstar[i], wih[i * 4 * DIM + t], gv);
      for (int i = 0; i < DIM; ++i) gv = fmaf(qh[i], whh[i * 4 * DIM + t], gv);
      gates[t] = gv;
    }
    __syncthreads();
    if (t < DIM) {
      const float ig = sigmoidf_(gates[t]);
      const float fg = sigmoidf_(gates[DIM + t]);
      const float gg = tanhf(gates[2 * DIM + t]);
      const float og = sigmoidf_(gates[3 * DIM + t]);
      const float c = fmaf(fg, qc[t], ig * gg);
      qc[t] = c;
      qh[t] = og * tanhf(c);
    }
    __syncthreads();
    float lmax = -INFINITY;
    for (int n = gs + t; n < ge; n += 256) {
      const float* orow = outf + n * DIM;
      float e = 0.0f;
#pragma unroll
      for (int d = 0; d < DIM; ++d) e = fmaf(orow[d], qh[d], e);
      lmax = fmaxf(lmax, e);
    }
#pragma unroll
    for (int off = 32; off > 0; off >>= 1) lmax = fmaxf(lmax, __shfl_xor(lmax, off));
    if (lane == 0) wmax[w] = lmax;
    __syncthreads();
    const float gmax = fmaxf(fmaxf(wmax[0], wmax[1]), fmaxf(wmax[2], wmax[3]));
    float rl[DIM];
#pragma unroll
    for (int d = 0; d < DIM; ++d) rl[d] = 0.0f;
    float lsum = 0.0f;
    for (int n = gs + t; n < ge; n += 256) {
      const float* orow = outf + n * DIM;
      float e = 0.0f;
#pragma unroll
      for (int d = 0; d < DIM; ++d) e = fmaf(orow[d], qh[d], e);
      const float a = expf(e - gmax);
      lsum += a;
#pragma unroll
      for (int d = 0; d < DIM; ++d) rl[d] = fmaf(a, orow[d], rl[d]);
    }
#pragma unroll
    for (int off = 32; off > 0; off >>= 1) {
      lsum += __shfl_xor(lsum, off);
#pragma unroll
      for (int d = 0; d < DIM; ++d) rl[d] += __shfl_xor(rl[d], off);
    }
    __syncthreads();
    if (lane == 0) {
      wsum[w] = lsum;
#pragma unroll
      for (int d = 0; d < DIM; ++d) wr[w][d] = rl[d];
    }
    __syncthreads();
    if (t < DIM) {
      const float stot = wsum[0] + wsum[1] + wsum[2] + wsum[3];
      const float rv = wr[0][t] + wr[1][t] + wr[2][t] + wr[3][t];
      qstar[t] = qh[t];
      qstar[DIM + t] = (stot > 0.0f) ? rv / stot : 0.0f;
    }
    __syncthreads();
  }
  if (t < DIM) {
    float u = l1b[t];
    for (int i = 0; i < 2 * DIM; ++i) u = fmaf(qstar[i], l1w[i * DIM + t], u);
    u = fmaxf(u, 0.0f);
    float v = u * l2w[t];
#pragma unroll
    for (int off = 16; off > 0; off >>= 1) v += __shfl_xor(v, off);
    if (t == 0) y[b] = v + l2b[0];
  }
}

extern "C" void kernel_launch(void* const* d_in, const int* in_sizes, int n_in,
                              void* d_out, int out_size, void* d_ws, size_t ws_size,
                              hipStream_t stream) {
  const float* x        = (const float*)d_in[0];
  const float* ea       = (const float*)d_in[1];
  const float* lin0_w   = (const float*)d_in[2];
  const float* lin0_b   = (const float*)d_in[3];
  const float* enn_w1   = (const float*)d_in[4];
  const float* enn_b1   = (const float*)d_in[5];
  const float* enn_w2   = (const float*)d_in[6];
  const float* enn_b2   = (const float*)d_in[7];
  const float* root_w   = (const float*)d_in[8];
  const float* conv_b   = (const float*)d_in[9];
  const float* gru_wih  = (const float*)d_in[10];
  const float* gru_whh  = (const float*)d_in[11];
  const float* gru_bih  = (const float*)d_in[12];
  const float* gru_bhh  = (const float*)d_in[13];
  const float* s2s_wih  = (const float*)d_in[14];
  const float* s2s_whh  = (const float*)d_in[15];
  const float* s2s_bih  = (const float*)d_in[16];
  const float* s2s_bhh  = (const float*)d_in[17];
  const float* lin1_w   = (const float*)d_in[18];
  const float* lin1_b   = (const float*)d_in[19];
  const float* lin2_w   = (const float*)d_in[20];
  const float* lin2_b   = (const float*)d_in[21];
  const int*   ei       = (const int*)d_in[22];
  const int*   batch    = (const int*)d_in[23];
  float* y = (float*)d_out;

  char* p = (char*)d_ws;
  auto alloc = [&](size_t bytes) -> void* {
    void* r = (void*)p;
    p += (bytes + 255) & ~(size_t)255;
    return r;
  };
  float*  out_a   = (float*)alloc(N_NODES * DIM * 4);
  float*  out_b   = (float*)alloc(N_NODES * DIM * 4);
  int*    counts  = (int*)alloc(N_NODES * 4);   // contiguous with cursor:
  int*    cursor  = (int*)alloc(N_NODES * 4);   // single 64 KB memset below
  int*    offsets = (int*)alloc((N_NODES + 1) * 4);
  int*    csr_src = (int*)alloc(N_EDGES * 4);
  float2* csr_ea  = (float2*)alloc(N_EDGES * 8);
  float*  deg_inv = (float*)alloc(N_NODES * 4);
  int*    gstart  = (int*)alloc((NGRAPH + 1) * 4);
  (void)ws_size; (void)n_in; (void)in_sizes; (void)out_size;

  hipMemsetAsync(counts, 0, 2 * N_NODES * 4, stream);  // counts + cursor

  prep1_kernel<<<1024 + 512, 256, 0, stream>>>(x, lin0_w, lin0_b, out_a,
                                               ei + N_EDGES, counts);
  scan_kernel<<<1, 1024, 0, stream>>>(counts, offsets, deg_inv);
  prep2_kernel<<<512 + 32, 256, 0, stream>>>(ei, ea, offsets, cursor, csr_src,
                                             csr_ea, batch, gstart);

  const int ngroups = N_NODES / G_NODES;  // 2048
  const float* cur = out_a;
  float* nxt = out_b;
  for (int layer = 0; layer < 3; ++layer) {
    mp_layer_kernel<<<ngroups, 256, 0, stream>>>(
        cur, offsets, csr_src, csr_ea, enn_w1, enn_b1, enn_w2, enn_b2,
        deg_inv, root_w, conv_b, gru_wih, gru_whh, gru_bih, gru_bhh, nxt);
    const float* tmp = cur; cur = nxt; nxt = (float*)tmp;
  }

  s2s_kernel<<<NGRAPH, 256, 0, stream>>>(cur, gstart, s2s_wih, s2s_whh, s2s_bih,
                                         s2s_bhh, lin1_w, lin1_b, lin2_w, lin2_b, y);
}

// Round 14
// 414.017 us; speedup vs baseline: 5.6758x; 1.0294x over previous
//
#include <hip/hip_runtime.h>

#define N_NODES 8192
#define N_EDGES 131072
#define NGRAPH  64
#define DIM     32
#define HID     128
#define KFULL   128
#define KHALF   64
#define G_NODES 4          // nodes per block (8192/4 = 2048 blocks)
#define SROW    36         // S d-stride: 16B-aligned; +swizzle for bank spread

__device__ __forceinline__ float sigmoidf_(float x) { return 1.0f / (1.0f + expf(-x)); }

// ---------------- prep (R3-verified) ----------------
__global__ void prep1_kernel(const float* __restrict__ x, const float* __restrict__ w,
                             const float* __restrict__ b, float* __restrict__ out,
                             const int* __restrict__ dst, int* __restrict__ counts) {
  const int bb = blockIdx.x;
  if (bb < 1024) {
    int idx = bb * 256 + threadIdx.x;
    int n = idx >> 5, d = idx & 31;
    out[idx] = fmaxf(fmaf(x[n], w[d], b[d]), 0.0f);
  } else {
    int e = (bb - 1024) * 256 + threadIdx.x;
    atomicAdd(&counts[dst[e]], 1);
  }
}

__global__ void scan_kernel(const int* __restrict__ counts,
                            int* __restrict__ offsets,
                            float* __restrict__ deg_inv) {
  __shared__ int sm[1024];
  int t = threadIdx.x;
  int base = t * 8;
  int loc[8];
  int s = 0;
#pragma unroll
  for (int i = 0; i < 8; ++i) { loc[i] = s; s += counts[base + i]; }
  sm[t] = s;
  __syncthreads();
  for (int off = 1; off < 1024; off <<= 1) {
    int v = (t >= off) ? sm[t - off] : 0;
    __syncthreads();
    sm[t] += v;
    __syncthreads();
  }
  int excl = (t > 0) ? sm[t - 1] : 0;
#pragma unroll
  for (int i = 0; i < 8; ++i) {
    offsets[base + i] = excl + loc[i];
    int c = counts[base + i];
    deg_inv[base + i] = 1.0f / (float)(c > 0 ? c : 1);
  }
  if (t == 1023) offsets[N_NODES] = sm[1023];
}

__global__ void prep2_kernel(const int* __restrict__ ei, const float* __restrict__ ea,
                             const int* __restrict__ offsets, int* __restrict__ cursor,
                             int* __restrict__ csr_src, float2* __restrict__ csr_ea,
                             const int* __restrict__ batch, int* __restrict__ gstart) {
  const int bb = blockIdx.x;
  if (bb < 512) {
    int e = bb * 256 + threadIdx.x;
    int d = ei[N_EDGES + e];
    int pos = atomicAdd(&cursor[d], 1);
    int slot = offsets[d] + pos;
    csr_src[slot] = ei[e];
    csr_ea[slot] = make_float2(ea[2 * e], ea[2 * e + 1]);
  } else {
    int n = (bb - 512) * 256 + threadIdx.x;
    int b = batch[n];
    if (n == 0) {
      for (int g = 0; g <= b; ++g) gstart[g] = 0;
    } else {
      int bp = batch[n - 1];
      for (int g = bp + 1; g <= b; ++g) gstart[g] = n;
    }
    if (n == N_NODES - 1) {
      for (int g = b + 1; g <= NGRAPH; ++g) gstart[g] = N_NODES;
    }
  }
}

// ---------------- fused MP layer: full-K edge loop (ONE pass), TWO-PASS contract,
// in-kernel epilogue. R12-verified numerics; launch_bounds(256,3) (was 4 ->
// VGPR cap 64 -> spill disaster). Cap ~170 fits the ~150-reg edge loop
// spill-free; 3 waves/SIMD -> 3 blocks/CU (LDS allows 4). ----------
__global__ __launch_bounds__(256, 3) void mp_layer_kernel(
    const float* __restrict__ out_cur, const int* __restrict__ offsets,
    const int* __restrict__ csr_src, const float2* __restrict__ csr_ea,
    const float* __restrict__ w1, const float* __restrict__ b1,
    const float* __restrict__ w2, const float* __restrict__ b2,
    const float* __restrict__ deg_inv, const float* __restrict__ root_w,
    const float* __restrict__ conv_b, const float* __restrict__ gwih,
    const float* __restrict__ gwhh, const float* __restrict__ gbih,
    const float* __restrict__ gbhh, float* __restrict__ out_nxt) {
  constexpr int C = 32;
  __shared__ float smem[G_NODES * KHALF * SROW];  // 9216 floats = 36864 B
  float* S = smem;
  float* hidb = smem;                  // C*KFULL = 4096 floats (aliases S)
  float* osrcb = smem + C * KFULL;     // C*DIM = 1024 floats (ends 5120 <= 9216)
  float* red = smem;                   // 16*257 = 4112 floats (aliases S)
  float* ob  = smem + 4352;            // 128 floats
  float* hb  = smem + 4480;            // 128
  float* mb  = smem + 4608;            // 128
  float* b2s = smem + 4736;            // 1024 (ends 5760 <= 9216)
  __shared__ int offs[G_NODES + 1];

  const int t = threadIdx.x;
  const int node0 = blockIdx.x * G_NODES;

  if (t <= G_NODES) offs[t] = offsets[node0 + t];

  // edge-compute map: (kg 0..31) x (dg 0..7); owns k0..k0+3 (of 128), d0..d0+3
  const int kg = t >> 3, dg = t & 7;
  const int k0 = kg * 4, d0 = dg * 4;
  // staging map: edge slot ec (0..31), sub (0..7) covers k = sub*16 .. sub*16+15
  const int ec = t >> 3, sub = t & 7;

  // hoist w1/b1 (16 k per staging thread)
  float w1x[16], w1y[16], b1v[16];
#pragma unroll
  for (int i = 0; i < 16; ++i) {
    const int kgl = sub * 16 + i;
    w1x[i] = w1[kgl];
    w1y[i] = w1[HID + kgl];
    b1v[i] = b1[kgl];
  }

  float acc[G_NODES][4][4];
#pragma unroll
  for (int g = 0; g < G_NODES; ++g)
#pragma unroll
    for (int i = 0; i < 4; ++i)
#pragma unroll
      for (int j = 0; j < 4; ++j) acc[g][i][j] = 0.0f;
  float oacc[G_NODES] = {};
  __syncthreads();  // offs visible

#pragma unroll
  for (int g = 0; g < G_NODES; ++g) {
    const int base = offs[g], end = offs[g + 1];
    for (int c0 = base; c0 < end; c0 += C) {
      const int cnt = min(C, end - c0);
      __syncthreads();  // previous chunk's readers done
      if (ec < cnt) {
        const int slot = c0 + ec;
        const float2 eav = csr_ea[slot];
        const int sidx = csr_src[slot];
        float hv[16];
#pragma unroll
        for (int i = 0; i < 16; ++i)
          hv[i] = fmaxf(fmaf(eav.y, w1y[i], fmaf(eav.x, w1x[i], b1v[i])), 0.0f);
#pragma unroll
        for (int j = 0; j < 4; ++j)
          *(float4*)(hidb + ec * KFULL + sub * 16 + j * 4) =
              make_float4(hv[j * 4], hv[j * 4 + 1], hv[j * 4 + 2], hv[j * 4 + 3]);
        *(float4*)(osrcb + ec * DIM + sub * 4) =
            *(const float4*)(out_cur + sidx * DIM + sub * 4);
      }
      __syncthreads();
      for (int e = 0; e < cnt; ++e) {
        const float4 hvv = *(const float4*)(hidb + e * KFULL + k0);
        const float4 ov = *(const float4*)(osrcb + e * DIM + d0);
        acc[g][0][0] = fmaf(hvv.x, ov.x, acc[g][0][0]);
        acc[g][0][1] = fmaf(hvv.x, ov.y, acc[g][0][1]);
        acc[g][0][2] = fmaf(hvv.x, ov.z, acc[g][0][2]);
        acc[g][0][3] = fmaf(hvv.x, ov.w, acc[g][0][3]);
        acc[g][1][0] = fmaf(hvv.y, ov.x, acc[g][1][0]);
        acc[g][1][1] = fmaf(hvv.y, ov.y, acc[g][1][1]);
        acc[g][1][2] = fmaf(hvv.y, ov.z, acc[g][1][2]);
        acc[g][1][3] = fmaf(hvv.y, ov.w, acc[g][1][3]);
        acc[g][2][0] = fmaf(hvv.z, ov.x, acc[g][2][0]);
        acc[g][2][1] = fmaf(hvv.z, ov.y, acc[g][2][1]);
        acc[g][2][2] = fmaf(hvv.z, ov.z, acc[g][2][2]);
        acc[g][2][3] = fmaf(hvv.z, ov.w, acc[g][2][3]);
        acc[g][3][0] = fmaf(hvv.w, ov.x, acc[g][3][0]);
        acc[g][3][1] = fmaf(hvv.w, ov.y, acc[g][3][1]);
        acc[g][3][2] = fmaf(hvv.w, ov.z, acc[g][3][2]);
        acc[g][3][3] = fmaf(hvv.w, ov.w, acc[g][3][3]);
        if (t < DIM) oacc[g] += osrcb[e * DIM + t];
      }
    }
  }
  __syncthreads();  // staging dead; S region reusable

  // ---- two-pass dump + contract over half-K S buffer (R12-verified) ----
  const int ks = t >> 4;          // contract map: (ks 0..15, dvh 0..1, og 0..7)
  const int dvh = (t >> 3) & 1;
  const int og = t & 7;
  float a4[G_NODES][4];
#pragma unroll
  for (int g = 0; g < G_NODES; ++g)
#pragma unroll
    for (int r = 0; r < 4; ++r) a4[g][r] = 0.0f;

#pragma unroll
  for (int p = 0; p < 2; ++p) {
    // dump rows k in [p*64, p*64+64): threads with kg>>4 == p
    if ((kg >> 4) == p) {
      const int kgl4 = (kg & 15) * 4;         // local row base 0..60
      const int shift = (kg & 3) * 8;         // == ((local row)>>2 & 3)*8
      const int dd = (d0 + shift) & 31;
#pragma unroll
      for (int g = 0; g < G_NODES; ++g) {
        float* Sg = S + g * KHALF * SROW;
#pragma unroll
        for (int i = 0; i < 4; ++i)
          *(float4*)(Sg + (kgl4 + i) * SROW + dd) =
              make_float4(acc[g][i][0], acc[g][i][1], acc[g][i][2], acc[g][i][3]);
      }
    }
    __syncthreads();
    // contract local rows 0..63 with w2 offset p*64 (R3-exact body)
#pragma unroll
    for (int i = 0; i < 4; ++i) {
      const int kl = ks * 4 + i;
      const int shift = (ks & 3) * 8;
      const float* w2k = w2 + (size_t)(p * KHALF + kl) * (DIM * DIM);
#pragma unroll
      for (int q = 0; q < 4; ++q) {
        const int dbase = dvh * 16 + q * 4;
        const int dq = (dbase + shift) & 31;
        const int soff = kl * SROW + dq;
        const float4 sv0 = *(const float4*)(S + 0 * KHALF * SROW + soff);
        const float4 sv1 = *(const float4*)(S + 1 * KHALF * SROW + soff);
        const float4 sv2 = *(const float4*)(S + 2 * KHALF * SROW + soff);
        const float4 sv3 = *(const float4*)(S + 3 * KHALF * SROW + soff);
        const float* s0 = (const float*)&sv0;
        const float* s1 = (const float*)&sv1;
        const float* s2 = (const float*)&sv2;
        const float* s3 = (const float*)&sv3;
#pragma unroll
        for (int r = 0; r < 4; ++r) {
          const float4 wv = *(const float4*)(w2k + (dbase + r) * DIM + og * 4);
          a4[0][0] = fmaf(s0[r], wv.x, a4[0][0]);
          a4[0][1] = fmaf(s0[r], wv.y, a4[0][1]);
          a4[0][2] = fmaf(s0[r], wv.z, a4[0][2]);
          a4[0][3] = fmaf(s0[r], wv.w, a4[0][3]);
          a4[1][0] = fmaf(s1[r], wv.x, a4[1][0]);
          a4[1][1] = fmaf(s1[r], wv.y, a4[1][1]);
          a4[1][2] = fmaf(s1[r], wv.z, a4[1][2]);
          a4[1][3] = fmaf(s1[r], wv.w, a4[1][3]);
          a4[2][0] = fmaf(s2[r], wv.x, a4[2][0]);
          a4[2][1] = fmaf(s2[r], wv.y, a4[2][1]);
          a4[2][2] = fmaf(s2[r], wv.z, a4[2][2]);
          a4[2][3] = fmaf(s2[r], wv.w, a4[2][3]);
          a4[3][0] = fmaf(s3[r], wv.x, a4[3][0]);
          a4[3][1] = fmaf(s3[r], wv.y, a4[3][1]);
          a4[3][2] = fmaf(s3[r], wv.z, a4[3][2]);
          a4[3][3] = fmaf(s3[r], wv.w, a4[3][3]);
        }
      }
    }
    __syncthreads();  // S reads done (pass-1 dump / red may overwrite)
  }

  // red write + epilogue input staging (disjoint LDS regions)
#pragma unroll
  for (int g = 0; g < G_NODES; ++g)
#pragma unroll
    for (int r = 0; r < 4; ++r) red[(g * 4 + r) * 257 + t] = a4[g][r];
  if (t < DIM) {
#pragma unroll
    for (int g = 0; g < G_NODES; ++g) ob[g * DIM + t] = oacc[g];
  }
  if (t < G_NODES * DIM) hb[t] = out_cur[node0 * DIM + t];
#pragma unroll
  for (int i = 0; i < 4; ++i) b2s[i * 256 + t] = b2[i * 256 + t];
  __syncthreads();

  // epilogue: reduce red + bias/root -> mb (R12-verified body)
  if (t < G_NODES * DIM) {
    const int g = t >> 5, o = t & 31;
    const int og2 = o >> 2, r2 = o & 3;
    const float* rp = red + (g * 4 + r2) * 257 + og2;
    float agg = 0.0f;
#pragma unroll
    for (int j = 0; j < 32; ++j) agg += rp[j * 8];
#pragma unroll
    for (int d = 0; d < DIM; ++d) agg = fmaf(ob[g * DIM + d], b2s[d * DIM + o], agg);
    agg *= deg_inv[node0 + g];
    float rt = conv_b[o];
#pragma unroll
    for (int d = 0; d < DIM; ++d) rt = fmaf(hb[g * DIM + d], root_w[d * DIM + o], rt);
    mb[t] = fmaxf(agg + rt, 0.0f);
  }
  __syncthreads();
  // GRU (R12-verified body)
  if (t < G_NODES * DIM) {
    const int g = t >> 5, o = t & 31;
    float gi[3], gh[3];
#pragma unroll
    for (int jj = 0; jj < 3; ++jj) {
      float si = gbih[jj * DIM + o], sh = gbhh[jj * DIM + o];
#pragma unroll
      for (int d = 0; d < DIM; ++d) {
        si = fmaf(mb[g * DIM + d], gwih[d * 3 * DIM + jj * DIM + o], si);
        sh = fmaf(hb[g * DIM + d], gwhh[d * 3 * DIM + jj * DIM + o], sh);
      }
      gi[jj] = si;
      gh[jj] = sh;
    }
    const float r = sigmoidf_(gi[0] + gh[0]);
    const float z = sigmoidf_(gi[1] + gh[1]);
    const float nn = tanhf(fmaf(r, gh[2], gi[2]));
    out_nxt[node0 * DIM + t] = (1.0f - z) * nn + z * hb[t];
  }
}

// ---------------- Set2Set + head (R3-verified) ----------------
__global__ __launch_bounds__(256) void s2s_kernel(
    const float* __restrict__ outf, const int* __restrict__ gstart,
    const float* __restrict__ wih, const float* __restrict__ whh,
    const float* __restrict__ bih, const float* __restrict__ bhh,
    const float* __restrict__ l1w, const float* __restrict__ l1b,
    const float* __restrict__ l2w, const float* __restrict__ l2b,
    float* __restrict__ y) {
  __shared__ float qh[DIM], qc[DIM], qstar[2 * DIM], gates[4 * DIM];
  __shared__ float wsum[4], wmax[4], wr[4][DIM];
  const int b = blockIdx.x, t = threadIdx.x;
  const int gs = gstart[b], ge = gstart[b + 1];
  const int w = t >> 6, lane = t & 63;
  if (t < DIM) { qh[t] = 0.0f; qc[t] = 0.0f; }
  if (t < 2 * DIM) qstar[t] = 0.0f;
  __syncthreads();
  for (int step = 0; step < 3; ++step) {
    if (t < 4 * DIM) {
      float gv = bih[t] + bhh[t];
      for (int i = 0; i < 2 * DIM; ++i) gv = fmaf(qstar[i], wih[i * 4 * DIM + t], gv);
      for (int i = 0; i < DIM; ++i) gv = fmaf(qh[i], whh[i * 4 * DIM + t], gv);
      gates[t] = gv;
    }
    __syncthreads();
    if (t < DIM) {
      const float ig = sigmoidf_(gates[t]);
      const float fg = sigmoidf_(gates[DIM + t]);
      const float gg = tanhf(gates[2 * DIM + t]);
      const float og = sigmoidf_(gates[3 * DIM + t]);
      const float c = fmaf(fg, qc[t], ig * gg);
      qc[t] = c;
      qh[t] = og * tanhf(c);
    }
    __syncthreads();
    float lmax = -INFINITY;
    for (int n = gs + t; n < ge; n += 256) {
      const float* orow = outf + n * DIM;
      float e = 0.0f;
#pragma unroll
      for (int d = 0; d < DIM; ++d) e = fmaf(orow[d], qh[d], e);
      lmax = fmaxf(lmax, e);
    }
#pragma unroll
    for (int off = 32; off > 0; off >>= 1) lmax = fmaxf(lmax, __shfl_xor(lmax, off));
    if (lane == 0) wmax[w] = lmax;
    __syncthreads();
    const float gmax = fmaxf(fmaxf(wmax[0], wmax[1]), fmaxf(wmax[2], wmax[3]));
    float rl[DIM];
#pragma unroll
    for (int d = 0; d < DIM; ++d) rl[d] = 0.0f;
    float lsum = 0.0f;
    for (int n = gs + t; n < ge; n += 256) {
      const float* orow = outf + n * DIM;
      float e = 0.0f;
#pragma unroll
      for (int d = 0; d < DIM; ++d) e = fmaf(orow[d], qh[d], e);
      const float a = expf(e - gmax);
      lsum += a;
#pragma unroll
      for (int d = 0; d < DIM; ++d) rl[d] = fmaf(a, orow[d], rl[d]);
    }
#pragma unroll
    for (int off = 32; off > 0; off >>= 1) {
      lsum += __shfl_xor(lsum, off);
#pragma unroll
      for (int d = 0; d < DIM; ++d) rl[d] += __shfl_xor(rl[d], off);
    }
    __syncthreads();
    if (lane == 0) {
      wsum[w] = lsum;
#pragma unroll
      for (int d = 0; d < DIM; ++d) wr[w][d] = rl[d];
    }
    __syncthreads();
    if (t < DIM) {
      const float stot = wsum[0] + wsum[1] + wsum[2] + wsum[3];
      const float rv = wr[0][t] + wr[1][t] + wr[2][t] + wr[3][t];
      qstar[t] = qh[t];
      qstar[DIM + t] = (stot > 0.0f) ? rv / stot : 0.0f;
    }
    __syncthreads();
  }
  if (t < DIM) {
    float u = l1b[t];
    for (int i = 0; i < 2 * DIM; ++i) u = fmaf(qstar[i], l1w[i * DIM + t], u);
    u = fmaxf(u, 0.0f);
    float v = u * l2w[t];
#pragma unroll
    for (int off = 16; off > 0; off >>= 1) v += __shfl_xor(v, off);
    if (t == 0) y[b] = v + l2b[0];
  }
}

extern "C" void kernel_launch(void* const* d_in, const int* in_sizes, int n_in,
                              void* d_out, int out_size, void* d_ws, size_t ws_size,
                              hipStream_t stream) {
  const float* x        = (const float*)d_in[0];
  const float* ea       = (const float*)d_in[1];
  const float* lin0_w   = (const float*)d_in[2];
  const float* lin0_b   = (const float*)d_in[3];
  const float* enn_w1   = (const float*)d_in[4];
  const float* enn_b1   = (const float*)d_in[5];
  const float* enn_w2   = (const float*)d_in[6];
  const float* enn_b2   = (const float*)d_in[7];
  const float* root_w   = (const float*)d_in[8];
  const float* conv_b   = (const float*)d_in[9];
  const float* gru_wih  = (const float*)d_in[10];
  const float* gru_whh  = (const float*)d_in[11];
  const float* gru_bih  = (const float*)d_in[12];
  const float* gru_bhh  = (const float*)d_in[13];
  const float* s2s_wih  = (const float*)d_in[14];
  const float* s2s_whh  = (const float*)d_in[15];
  const float* s2s_bih  = (const float*)d_in[16];
  const float* s2s_bhh  = (const float*)d_in[17];
  const float* lin1_w   = (const float*)d_in[18];
  const float* lin1_b   = (const float*)d_in[19];
  const float* lin2_w   = (const float*)d_in[20];
  const float* lin2_b   = (const float*)d_in[21];
  const int*   ei       = (const int*)d_in[22];
  const int*   batch    = (const int*)d_in[23];
  float* y = (float*)d_out;

  char* p = (char*)d_ws;
  auto alloc = [&](size_t bytes) -> void* {
    void* r = (void*)p;
    p += (bytes + 255) & ~(size_t)255;
    return r;
  };
  float*  out_a   = (float*)alloc(N_NODES * DIM * 4);
  float*  out_b   = (float*)alloc(N_NODES * DIM * 4);
  int*    counts  = (int*)alloc(N_NODES * 4);   // contiguous with cursor:
  int*    cursor  = (int*)alloc(N_NODES * 4);   // single 64 KB memset below
  int*    offsets = (int*)alloc((N_NODES + 1) * 4);
  int*    csr_src = (int*)alloc(N_EDGES * 4);
  float2* csr_ea  = (float2*)alloc(N_EDGES * 8);
  float*  deg_inv = (float*)alloc(N_NODES * 4);
  int*    gstart  = (int*)alloc((NGRAPH + 1) * 4);
  (void)ws_size; (void)n_in; (void)in_sizes; (void)out_size;

  hipMemsetAsync(counts, 0, 2 * N_NODES * 4, stream);  // counts + cursor

  prep1_kernel<<<1024 + 512, 256, 0, stream>>>(x, lin0_w, lin0_b, out_a,
                                               ei + N_EDGES, counts);
  scan_kernel<<<1, 1024, 0, stream>>>(counts, offsets, deg_inv);
  prep2_kernel<<<512 + 32, 256, 0, stream>>>(ei, ea, offsets, cursor, csr_src,
                                             csr_ea, batch, gstart);

  const int ngroups = N_NODES / G_NODES;  // 2048
  const float* cur = out_a;
  float* nxt = out_b;
  for (int layer = 0; layer < 3; ++layer) {
    mp_layer_kernel<<<ngroups, 256, 0, stream>>>(
        cur, offsets, csr_src, csr_ea, enn_w1, enn_b1, enn_w2, enn_b2,
        deg_inv, root_w, conv_b, gru_wih, gru_whh, gru_bih, gru_bhh, nxt);
    const float* tmp = cur; cur = nxt; nxt = (float*)tmp;
  }

  s2s_kernel<<<NGRAPH, 256, 0, stream>>>(cur, gstart, s2s_wih, s2s_whh, s2s_bih,
                                         s2s_bhh, lin1_w, lin1_b, lin2_w, lin2_b, y);
}

// Round 15
// 406.564 us; speedup vs baseline: 5.7799x; 1.0183x over previous
//
#include <hip/hip_runtime.h>

#define N_NODES 8192
#define N_EDGES 131072
#define NGRAPH  64
#define DIM     32
#define HID     128
#define KFULL   128
#define KHALF   64
#define G_NODES 4          // nodes per block (8192/4 = 2048 blocks)
#define SROW    36         // S d-stride: 16B-aligned; +swizzle for bank spread

__device__ __forceinline__ float sigmoidf_(float x) { return 1.0f / (1.0f + expf(-x)); }

// ---------------- prep (R3-verified) ----------------
__global__ void prep1_kernel(const float* __restrict__ x, const float* __restrict__ w,
                             const float* __restrict__ b, float* __restrict__ out,
                             const int* __restrict__ dst, int* __restrict__ counts) {
  const int bb = blockIdx.x;
  if (bb < 1024) {
    int idx = bb * 256 + threadIdx.x;
    int n = idx >> 5, d = idx & 31;
    out[idx] = fmaxf(fmaf(x[n], w[d], b[d]), 0.0f);
  } else {
    int e = (bb - 1024) * 256 + threadIdx.x;
    atomicAdd(&counts[dst[e]], 1);
  }
}

__global__ void scan_kernel(const int* __restrict__ counts,
                            int* __restrict__ offsets,
                            float* __restrict__ deg_inv) {
  __shared__ int sm[1024];
  int t = threadIdx.x;
  int base = t * 8;
  int loc[8];
  int s = 0;
#pragma unroll
  for (int i = 0; i < 8; ++i) { loc[i] = s; s += counts[base + i]; }
  sm[t] = s;
  __syncthreads();
  for (int off = 1; off < 1024; off <<= 1) {
    int v = (t >= off) ? sm[t - off] : 0;
    __syncthreads();
    sm[t] += v;
    __syncthreads();
  }
  int excl = (t > 0) ? sm[t - 1] : 0;
#pragma unroll
  for (int i = 0; i < 8; ++i) {
    offsets[base + i] = excl + loc[i];
    int c = counts[base + i];
    deg_inv[base + i] = 1.0f / (float)(c > 0 ? c : 1);
  }
  if (t == 1023) offsets[N_NODES] = sm[1023];
}

__global__ void prep2_kernel(const int* __restrict__ ei, const float* __restrict__ ea,
                             const int* __restrict__ offsets, int* __restrict__ cursor,
                             int* __restrict__ csr_src, float2* __restrict__ csr_ea,
                             const int* __restrict__ batch, int* __restrict__ gstart) {
  const int bb = blockIdx.x;
  if (bb < 512) {
    int e = bb * 256 + threadIdx.x;
    int d = ei[N_EDGES + e];
    int pos = atomicAdd(&cursor[d], 1);
    int slot = offsets[d] + pos;
    csr_src[slot] = ei[e];
    csr_ea[slot] = make_float2(ea[2 * e], ea[2 * e + 1]);
  } else {
    int n = (bb - 512) * 256 + threadIdx.x;
    int b = batch[n];
    if (n == 0) {
      for (int g = 0; g <= b; ++g) gstart[g] = 0;
    } else {
      int bp = batch[n - 1];
      for (int g = bp + 1; g <= b; ++g) gstart[g] = n;
    }
    if (n == N_NODES - 1) {
      for (int g = b + 1; g <= NGRAPH; ++g) gstart[g] = N_NODES;
    }
  }
}

// ---------------- fused MP layer: full-K edge loop (ONE pass), TWO-PASS contract,
// in-kernel epilogue (R14-verified, 414 µs). This round: cut edge-loop register
// demand to kill the partial spill seen in R14 (VGPR 84 + 21.5 MB scratch):
// (1) w1/b1 hoist moved to LDS [5120..5504) — free during edge loop, dead after;
// (2) hv[16] -> hv4 per-j (live range 4). ----------
__global__ __launch_bounds__(256, 3) void mp_layer_kernel(
    const float* __restrict__ out_cur, const int* __restrict__ offsets,
    const int* __restrict__ csr_src, const float2* __restrict__ csr_ea,
    const float* __restrict__ w1, const float* __restrict__ b1,
    const float* __restrict__ w2, const float* __restrict__ b2,
    const float* __restrict__ deg_inv, const float* __restrict__ root_w,
    const float* __restrict__ conv_b, const float* __restrict__ gwih,
    const float* __restrict__ gwhh, const float* __restrict__ gbih,
    const float* __restrict__ gbhh, float* __restrict__ out_nxt) {
  constexpr int C = 32;
  __shared__ float smem[G_NODES * KHALF * SROW];  // 9216 floats = 36864 B
  float* S = smem;
  float* hidb = smem;                  // C*KFULL = 4096 floats (aliases S)
  float* osrcb = smem + C * KFULL;     // C*DIM = 1024 floats (ends 5120)
  float* w1s  = smem + 5120;           // 3*HID = 384 floats (ends 5504; edge-loop only)
  float* red = smem;                   // 16*257 = 4112 floats (aliases S)
  float* ob  = smem + 4352;            // 128 floats
  float* hb  = smem + 4480;            // 128
  float* mb  = smem + 4608;            // 128
  float* b2s = smem + 4736;            // 1024 (ends 5760 <= 9216)
  __shared__ int offs[G_NODES + 1];

  const int t = threadIdx.x;
  const int node0 = blockIdx.x * G_NODES;

  if (t <= G_NODES) offs[t] = offsets[node0 + t];
  // stage w1/b1 into LDS (read per chunk by staging threads; dead after edge loop)
  if (t < HID) {
    w1s[t] = w1[t];
    w1s[HID + t] = w1[HID + t];
    w1s[2 * HID + t] = b1[t];
  }

  // edge-compute map: (kg 0..31) x (dg 0..7); owns k0..k0+3 (of 128), d0..d0+3
  const int kg = t >> 3, dg = t & 7;
  const int k0 = kg * 4, d0 = dg * 4;
  // staging map: edge slot ec (0..31), sub (0..7) covers k = sub*16 .. sub*16+15
  const int ec = t >> 3, sub = t & 7;

  float acc[G_NODES][4][4];
#pragma unroll
  for (int g = 0; g < G_NODES; ++g)
#pragma unroll
    for (int i = 0; i < 4; ++i)
#pragma unroll
      for (int j = 0; j < 4; ++j) acc[g][i][j] = 0.0f;
  float oacc[G_NODES] = {};
  __syncthreads();  // offs + w1s visible

#pragma unroll
  for (int g = 0; g < G_NODES; ++g) {
    const int base = offs[g], end = offs[g + 1];
    for (int c0 = base; c0 < end; c0 += C) {
      const int cnt = min(C, end - c0);
      __syncthreads();  // previous chunk's readers done
      if (ec < cnt) {
        const int slot = c0 + ec;
        const float2 eav = csr_ea[slot];
        const int sidx = csr_src[slot];
#pragma unroll
        for (int j = 0; j < 4; ++j) {
          const float4 wx = *(const float4*)(w1s + sub * 16 + j * 4);
          const float4 wy = *(const float4*)(w1s + HID + sub * 16 + j * 4);
          const float4 wb = *(const float4*)(w1s + 2 * HID + sub * 16 + j * 4);
          float4 hv4;
          hv4.x = fmaxf(fmaf(eav.y, wy.x, fmaf(eav.x, wx.x, wb.x)), 0.0f);
          hv4.y = fmaxf(fmaf(eav.y, wy.y, fmaf(eav.x, wx.y, wb.y)), 0.0f);
          hv4.z = fmaxf(fmaf(eav.y, wy.z, fmaf(eav.x, wx.z, wb.z)), 0.0f);
          hv4.w = fmaxf(fmaf(eav.y, wy.w, fmaf(eav.x, wx.w, wb.w)), 0.0f);
          *(float4*)(hidb + ec * KFULL + sub * 16 + j * 4) = hv4;
        }
        *(float4*)(osrcb + ec * DIM + sub * 4) =
            *(const float4*)(out_cur + sidx * DIM + sub * 4);
      }
      __syncthreads();
      for (int e = 0; e < cnt; ++e) {
        const float4 hvv = *(const float4*)(hidb + e * KFULL + k0);
        const float4 ov = *(const float4*)(osrcb + e * DIM + d0);
        acc[g][0][0] = fmaf(hvv.x, ov.x, acc[g][0][0]);
        acc[g][0][1] = fmaf(hvv.x, ov.y, acc[g][0][1]);
        acc[g][0][2] = fmaf(hvv.x, ov.z, acc[g][0][2]);
        acc[g][0][3] = fmaf(hvv.x, ov.w, acc[g][0][3]);
        acc[g][1][0] = fmaf(hvv.y, ov.x, acc[g][1][0]);
        acc[g][1][1] = fmaf(hvv.y, ov.y, acc[g][1][1]);
        acc[g][1][2] = fmaf(hvv.y, ov.z, acc[g][1][2]);
        acc[g][1][3] = fmaf(hvv.y, ov.w, acc[g][1][3]);
        acc[g][2][0] = fmaf(hvv.z, ov.x, acc[g][2][0]);
        acc[g][2][1] = fmaf(hvv.z, ov.y, acc[g][2][1]);
        acc[g][2][2] = fmaf(hvv.z, ov.z, acc[g][2][2]);
        acc[g][2][3] = fmaf(hvv.z, ov.w, acc[g][2][3]);
        acc[g][3][0] = fmaf(hvv.w, ov.x, acc[g][3][0]);
        acc[g][3][1] = fmaf(hvv.w, ov.y, acc[g][3][1]);
        acc[g][3][2] = fmaf(hvv.w, ov.z, acc[g][3][2]);
        acc[g][3][3] = fmaf(hvv.w, ov.w, acc[g][3][3]);
        if (t < DIM) oacc[g] += osrcb[e * DIM + t];
      }
    }
  }
  __syncthreads();  // staging dead; S region reusable

  // ---- two-pass dump + contract over half-K S buffer (R12/R14-verified) ----
  const int ks = t >> 4;          // contract map: (ks 0..15, dvh 0..1, og 0..7)
  const int dvh = (t >> 3) & 1;
  const int og = t & 7;
  float a4[G_NODES][4];
#pragma unroll
  for (int g = 0; g < G_NODES; ++g)
#pragma unroll
    for (int r = 0; r < 4; ++r) a4[g][r] = 0.0f;

#pragma unroll
  for (int p = 0; p < 2; ++p) {
    // dump rows k in [p*64, p*64+64): threads with kg>>4 == p
    if ((kg >> 4) == p) {
      const int kgl4 = (kg & 15) * 4;         // local row base 0..60
      const int shift = (kg & 3) * 8;         // == ((local row)>>2 & 3)*8
      const int dd = (d0 + shift) & 31;
#pragma unroll
      for (int g = 0; g < G_NODES; ++g) {
        float* Sg = S + g * KHALF * SROW;
#pragma unroll
        for (int i = 0; i < 4; ++i)
          *(float4*)(Sg + (kgl4 + i) * SROW + dd) =
              make_float4(acc[g][i][0], acc[g][i][1], acc[g][i][2], acc[g][i][3]);
      }
    }
    __syncthreads();
    // contract local rows 0..63 with w2 offset p*64 (R3-exact body)
#pragma unroll
    for (int i = 0; i < 4; ++i) {
      const int kl = ks * 4 + i;
      const int shift = (ks & 3) * 8;
      const float* w2k = w2 + (size_t)(p * KHALF + kl) * (DIM * DIM);
#pragma unroll
      for (int q = 0; q < 4; ++q) {
        const int dbase = dvh * 16 + q * 4;
        const int dq = (dbase + shift) & 31;
        const int soff = kl * SROW + dq;
        const float4 sv0 = *(const float4*)(S + 0 * KHALF * SROW + soff);
        const float4 sv1 = *(const float4*)(S + 1 * KHALF * SROW + soff);
        const float4 sv2 = *(const float4*)(S + 2 * KHALF * SROW + soff);
        const float4 sv3 = *(const float4*)(S + 3 * KHALF * SROW + soff);
        const float* s0 = (const float*)&sv0;
        const float* s1 = (const float*)&sv1;
        const float* s2 = (const float*)&sv2;
        const float* s3 = (const float*)&sv3;
#pragma unroll
        for (int r = 0; r < 4; ++r) {
          const float4 wv = *(const float4*)(w2k + (dbase + r) * DIM + og * 4);
          a4[0][0] = fmaf(s0[r], wv.x, a4[0][0]);
          a4[0][1] = fmaf(s0[r], wv.y, a4[0][1]);
          a4[0][2] = fmaf(s0[r], wv.z, a4[0][2]);
          a4[0][3] = fmaf(s0[r], wv.w, a4[0][3]);
          a4[1][0] = fmaf(s1[r], wv.x, a4[1][0]);
          a4[1][1] = fmaf(s1[r], wv.y, a4[1][1]);
          a4[1][2] = fmaf(s1[r], wv.z, a4[1][2]);
          a4[1][3] = fmaf(s1[r], wv.w, a4[1][3]);
          a4[2][0] = fmaf(s2[r], wv.x, a4[2][0]);
          a4[2][1] = fmaf(s2[r], wv.y, a4[2][1]);
          a4[2][2] = fmaf(s2[r], wv.z, a4[2][2]);
          a4[2][3] = fmaf(s2[r], wv.w, a4[2][3]);
          a4[3][0] = fmaf(s3[r], wv.x, a4[3][0]);
          a4[3][1] = fmaf(s3[r], wv.y, a4[3][1]);
          a4[3][2] = fmaf(s3[r], wv.z, a4[3][2]);
          a4[3][3] = fmaf(s3[r], wv.w, a4[3][3]);
        }
      }
    }
    __syncthreads();  // S reads done (pass-1 dump / red may overwrite)
  }

  // red write + epilogue input staging (disjoint LDS regions)
#pragma unroll
  for (int g = 0; g < G_NODES; ++g)
#pragma unroll
    for (int r = 0; r < 4; ++r) red[(g * 4 + r) * 257 + t] = a4[g][r];
  if (t < DIM) {
#pragma unroll
    for (int g = 0; g < G_NODES; ++g) ob[g * DIM + t] = oacc[g];
  }
  if (t < G_NODES * DIM) hb[t] = out_cur[node0 * DIM + t];
#pragma unroll
  for (int i = 0; i < 4; ++i) b2s[i * 256 + t] = b2[i * 256 + t];
  __syncthreads();

  // epilogue: reduce red + bias/root -> mb (R12/R14-verified body)
  if (t < G_NODES * DIM) {
    const int g = t >> 5, o = t & 31;
    const int og2 = o >> 2, r2 = o & 3;
    const float* rp = red + (g * 4 + r2) * 257 + og2;
    float agg = 0.0f;
#pragma unroll
    for (int j = 0; j < 32; ++j) agg += rp[j * 8];
#pragma unroll
    for (int d = 0; d < DIM; ++d) agg = fmaf(ob[g * DIM + d], b2s[d * DIM + o], agg);
    agg *= deg_inv[node0 + g];
    float rt = conv_b[o];
#pragma unroll
    for (int d = 0; d < DIM; ++d) rt = fmaf(hb[g * DIM + d], root_w[d * DIM + o], rt);
    mb[t] = fmaxf(agg + rt, 0.0f);
  }
  __syncthreads();
  // GRU (R12/R14-verified body)
  if (t < G_NODES * DIM) {
    const int g = t >> 5, o = t & 31;
    float gi[3], gh[3];
#pragma unroll
    for (int jj = 0; jj < 3; ++jj) {
      float si = gbih[jj * DIM + o], sh = gbhh[jj * DIM + o];
#pragma unroll
      for (int d = 0; d < DIM; ++d) {
        si = fmaf(mb[g * DIM + d], gwih[d * 3 * DIM + jj * DIM + o], si);
        sh = fmaf(hb[g * DIM + d], gwhh[d * 3 * DIM + jj * DIM + o], sh);
      }
      gi[jj] = si;
      gh[jj] = sh;
    }
    const float r = sigmoidf_(gi[0] + gh[0]);
    const float z = sigmoidf_(gi[1] + gh[1]);
    const float nn = tanhf(fmaf(r, gh[2], gi[2]));
    out_nxt[node0 * DIM + t] = (1.0f - z) * nn + z * hb[t];
  }
}

// ---------------- Set2Set + head (R3-verified) ----------------
__global__ __launch_bounds__(256) void s2s_kernel(
    const float* __restrict__ outf, const int* __restrict__ gstart,
    const float* __restrict__ wih, const float* __restrict__ whh,
    const float* __restrict__ bih, const float* __restrict__ bhh,
    const float* __restrict__ l1w, const float* __restrict__ l1b,
    const float* __restrict__ l2w, const float* __restrict__ l2b,
    float* __restrict__ y) {
  __shared__ float qh[DIM], qc[DIM], qstar[2 * DIM], gates[4 * DIM];
  __shared__ float wsum[4], wmax[4], wr[4][DIM];
  const int b = blockIdx.x, t = threadIdx.x;
  const int gs = gstart[b], ge = gstart[b + 1];
  const int w = t >> 6, lane = t & 63;
  if (t < DIM) { qh[t] = 0.0f; qc[t] = 0.0f; }
  if (t < 2 * DIM) qstar[t] = 0.0f;
  __syncthreads();
  for (int step = 0; step < 3; ++step) {
    if (t < 4 * DIM) {
      float gv = bih[t] + bhh[t];
      for (int i = 0; i < 2 * DIM; ++i) gv = fmaf(qstar[i], wih[i * 4 * DIM + t], gv);
      for (int i = 0; i < DIM; ++i) gv = fmaf(qh[i], whh[i * 4 * DIM + t], gv);
      gates[t] = gv;
    }
    __syncthreads();
    if (t < DIM) {
      const float ig = sigmoidf_(gates[t]);
      const float fg = sigmoidf_(gates[DIM + t]);
      const float gg = tanhf(gates[2 * DIM + t]);
      const float og = sigmoidf_(gates[3 * DIM + t]);
      const float c = fmaf(fg, qc[t], ig * gg);
      qc[t] = c;
      qh[t] = og * tanhf(c);
    }
    __syncthreads();
    float lmax = -INFINITY;
    for (int n = gs + t; n < ge; n += 256) {
      const float* orow = outf + n * DIM;
      float e = 0.0f;
#pragma unroll
      for (int d = 0; d < DIM; ++d) e = fmaf(orow[d], qh[d], e);
      lmax = fmaxf(lmax, e);
    }
#pragma unroll
    for (int off = 32; off > 0; off >>= 1) lmax = fmaxf(lmax, __shfl_xor(lmax, off));
    if (lane == 0) wmax[w] = lmax;
    __syncthreads();
    const float gmax = fmaxf(fmaxf(wmax[0], wmax[1]), fmaxf(wmax[2], wmax[3]));
    float rl[DIM];
#pragma unroll
    for (int d = 0; d < DIM; ++d) rl[d] = 0.0f;
    float lsum = 0.0f;
    for (int n = gs + t; n < ge; n += 256) {
      const float* orow = outf + n * DIM;
      float e = 0.0f;
#pragma unroll
      for (int d = 0; d < DIM; ++d) e = fmaf(orow[d], qh[d], e);
      const float a = expf(e - gmax);
      lsum += a;
#pragma unroll
      for (int d = 0; d < DIM; ++d) rl[d] = fmaf(a, orow[d], rl[d]);
    }
#pragma unroll
    for (int off = 32; off > 0; off >>= 1) {
      lsum += __shfl_xor(lsum, off);
#pragma unroll
      for (int d = 0; d < DIM; ++d) rl[d] += __shfl_xor(rl[d], off);
    }
    __syncthreads();
    if (lane == 0) {
      wsum[w] = lsum;
#pragma unroll
      for (int d = 0; d < DIM; ++d) wr[w][d] = rl[d];
    }
    __syncthreads();
    if (t < DIM) {
      const float stot = wsum[0] + wsum[1] + wsum[2] + wsum[3];
      const float rv = wr[0][t] + wr[1][t] + wr[2][t] + wr[3][t];
      qstar[t] = qh[t];
      qstar[DIM + t] = (stot > 0.0f) ? rv / stot : 0.0f;
    }
    __syncthreads();
  }
  if (t < DIM) {
    float u = l1b[t];
    for (int i = 0; i < 2 * DIM; ++i) u = fmaf(qstar[i], l1w[i * DIM + t], u);
    u = fmaxf(u, 0.0f);
    float v = u * l2w[t];
#pragma unroll
    for (int off = 16; off > 0; off >>= 1) v += __shfl_xor(v, off);
    if (t == 0) y[b] = v + l2b[0];
  }
}

extern "C" void kernel_launch(void* const* d_in, const int* in_sizes, int n_in,
                              void* d_out, int out_size, void* d_ws, size_t ws_size,
                              hipStream_t stream) {
  const float* x        = (const float*)d_in[0];
  const float* ea       = (const float*)d_in[1];
  const float* lin0_w   = (const float*)d_in[2];
  const float* lin0_b   = (const float*)d_in[3];
  const float* enn_w1   = (const float*)d_in[4];
  const float* enn_b1   = (const float*)d_in[5];
  const float* enn_w2   = (const float*)d_in[6];
  const float* enn_b2   = (const float*)d_in[7];
  const float* root_w   = (const float*)d_in[8];
  const float* conv_b   = (const float*)d_in[9];
  const float* gru_wih  = (const float*)d_in[10];
  const float* gru_whh  = (const float*)d_in[11];
  const float* gru_bih  = (const float*)d_in[12];
  const float* gru_bhh  = (const float*)d_in[13];
  const float* s2s_wih  = (const float*)d_in[14];
  const float* s2s_whh  = (const float*)d_in[15];
  const float* s2s_bih  = (const float*)d_in[16];
  const float* s2s_bhh  = (const float*)d_in[17];
  const float* lin1_w   = (const float*)d_in[18];
  const float* lin1_b   = (const float*)d_in[19];
  const float* lin2_w   = (const float*)d_in[20];
  const float* lin2_b   = (const float*)d_in[21];
  const int*   ei       = (const int*)d_in[22];
  const int*   batch    = (const int*)d_in[23];
  float* y = (float*)d_out;

  char* p = (char*)d_ws;
  auto alloc = [&](size_t bytes) -> void* {
    void* r = (void*)p;
    p += (bytes + 255) & ~(size_t)255;
    return r;
  };
  float*  out_a   = (float*)alloc(N_NODES * DIM * 4);
  float*  out_b   = (float*)alloc(N_NODES * DIM * 4);
  int*    counts  = (int*)alloc(N_NODES * 4);   // contiguous with cursor:
  int*    cursor  = (int*)alloc(N_NODES * 4);   // single 64 KB memset below
  int*    offsets = (int*)alloc((N_NODES + 1) * 4);
  int*    csr_src = (int*)alloc(N_EDGES * 4);
  float2* csr_ea  = (float2*)alloc(N_EDGES * 8);
  float*  deg_inv = (float*)alloc(N_NODES * 4);
  int*    gstart  = (int*)alloc((NGRAPH + 1) * 4);
  (void)ws_size; (void)n_in; (void)in_sizes; (void)out_size;

  hipMemsetAsync(counts, 0, 2 * N_NODES * 4, stream);  // counts + cursor

  prep1_kernel<<<1024 + 512, 256, 0, stream>>>(x, lin0_w, lin0_b, out_a,
                                               ei + N_EDGES, counts);
  scan_kernel<<<1, 1024, 0, stream>>>(counts, offsets, deg_inv);
  prep2_kernel<<<512 + 32, 256, 0, stream>>>(ei, ea, offsets, cursor, csr_src,
                                             csr_ea, batch, gstart);

  const int ngroups = N_NODES / G_NODES;  // 2048
  const float* cur = out_a;
  float* nxt = out_b;
  for (int layer = 0; layer < 3; ++layer) {
    mp_layer_kernel<<<ngroups, 256, 0, stream>>>(
        cur, offsets, csr_src, csr_ea, enn_w1, enn_b1, enn_w2, enn_b2,
        deg_inv, root_w, conv_b, gru_wih, gru_whh, gru_bih, gru_bhh, nxt);
    const float* tmp = cur; cur = nxt; nxt = (float*)tmp;
  }

  s2s_kernel<<<NGRAPH, 256, 0, stream>>>(cur, gstart, s2s_wih, s2s_whh, s2s_bih,
                                         s2s_bhh, lin1_w, lin1_b, lin2_w, lin2_b, y);
}